// Round 10
// baseline (395.237 us; speedup 1.0000x reference)
//
#include <hip/hip_runtime.h>
#include <hip/hip_bf16.h>

typedef __attribute__((ext_vector_type(8))) __bf16 bf16x8;
typedef __attribute__((ext_vector_type(4))) float f32x4;
typedef __attribute__((ext_vector_type(8))) unsigned short ushort8;
typedef unsigned short ushort;

__device__ __forceinline__ ushort f2bf(float f) {
    unsigned u = __builtin_bit_cast(unsigned, f);
    unsigned r = (u + 0x7fffu + ((u >> 16) & 1u)) >> 16;
    return (ushort)r;
}

__device__ __forceinline__ unsigned cvtpk(float a, float b) {
    unsigned r;
    asm("v_cvt_pk_bf16_f32 %0, %1, %2" : "=v"(r) : "v"(a), "v"(b));
    return r;
}

// ---------------------------------------------------------------------------
// Pack layer-1 weights (4x [512,256] fp32) and layer-2 weights into bf16
// MFMA-B-fragment order in ws. (unchanged)
// W1p ushort offset = w*131072 + cg*32768 + nf*8192 + it*1024 + ks*512 + l*8
// ---------------------------------------------------------------------------
__global__ __launch_bounds__(256) void k_pack(
    const float* __restrict__ w1a, const float* __restrict__ w1b,
    const float* __restrict__ w1c, const float* __restrict__ w1d,
    const float* __restrict__ w2a, const float* __restrict__ w2b,
    const float* __restrict__ w2c, const float* __restrict__ w2d,
    ushort* __restrict__ W1p, ushort* __restrict__ W2p)
{
    int c = blockIdx.x * 256 + threadIdx.x;
    if (c < 65536) {
        int l = c & 63, ks = (c >> 6) & 15, n16 = c >> 10;
        int j = n16 >> 4;
        int col = (n16 & 15) * 16 + (l & 15);
        int kb = ks * 32 + (l >> 4) * 8;
        const float* W = (j == 0) ? w1a : (j == 1) ? w1b : (j == 2) ? w1c : w1d;
        ushort8 o;
#pragma unroll
        for (int e = 0; e < 8; ++e) o[e] = f2bf(W[(size_t)(kb + e) * 256 + col]);
        *reinterpret_cast<ushort8*>(W1p + (size_t)c * 8) = o;
    } else if (c < 65536 + 10752) {
        int cc = c - 65536;
        int l = cc & 63, ks = (cc >> 6) & 7, f = cc >> 9;
        int colg = f * 16 + (l & 15);
        int kb = ks * 32 + (l >> 4) * 8;
        const float* W = nullptr; int lc = 0, ncols = 1;
        if (colg < 192)        { W = w2a; lc = colg;       ncols = 192; }
        else if (colg < 256)   { W = w2b; lc = colg - 192; ncols = 64; }
        else if (colg < 320)   { W = w2c; lc = colg - 256; ncols = 64; }
        else if (colg == 320)  { W = w2d; lc = 0;          ncols = 1; }
        ushort8 o;
#pragma unroll
        for (int e = 0; e < 8; ++e)
            o[e] = W ? f2bf(W[(size_t)(kb + e) * ncols + lc]) : (ushort)0;
        *reinterpret_cast<ushort8*>(W2p + (size_t)cc * 8) = o;
    }
}

// ---------------------------------------------------------------------------
// Layer-1 GEMM (R7 structure, production): 64 rows x 1024 cols, 4 waves,
// dist-2 B ring, fully unrolled 32 steps. 165.9 us total config.
// ---------------------------------------------------------------------------
__global__ __launch_bounds__(256) void k_l1(
    const float* __restrict__ S, const ushort* __restrict__ W1p,
    const float* __restrict__ b0, const float* __restrict__ b1,
    const float* __restrict__ b2, const float* __restrict__ b3,
    ushort* __restrict__ hid, int m0)
{
    __shared__ ushort sA[64 * 512];
    __shared__ ushort sT[4][64 * 20];
    char* sAb = reinterpret_cast<char*>(sA);

    int tid = threadIdx.x, l = tid & 63, w = tid >> 6;
    int lr = l & 15, lg = l >> 4;
    int mt = blockIdx.x;
    const float* Srow = S + (size_t)(m0 + mt * 64) * 512;
    const ushort* Wb = W1p + (size_t)w * 131072 + (size_t)l * 8;

    bf16x8 ring[3][8];
#pragma unroll
    for (int p = 0; p < 2; ++p)
#pragma unroll
        for (int ks = 0; ks < 2; ++ks)
#pragma unroll
            for (int nf = 0; nf < 4; ++nf)
                ring[p][ks * 4 + nf] = *reinterpret_cast<const bf16x8*>(
                    Wb + nf * 8192 + p * 1024 + ks * 512);

#pragma unroll
    for (int i = 0; i < 16; ++i) {
        int c = i * 256 + tid;
        int row = c >> 6, kc = c & 63;
        const float4* g = reinterpret_cast<const float4*>(Srow + (size_t)row * 512 + kc * 8);
        float4 fa = g[0], fb = g[1];
        uint4 o;
        o.x = cvtpk(fa.x, fa.y); o.y = cvtpk(fa.z, fa.w);
        o.z = cvtpk(fb.x, fb.y); o.w = cvtpk(fb.z, fb.w);
        *reinterpret_cast<uint4*>(sAb + (size_t)(row * 64 + (kc ^ (row & 7))) * 16) = o;
    }
    __syncthreads();

    const float* bp = (w == 0) ? b0 : (w == 1) ? b1 : (w == 2) ? b2 : b3;
    ushort* myT = sT[w];

#pragma unroll
    for (int cg = 0; cg < 4; ++cg) {
        f32x4 acc[4][4] = {{{0.f}}};
#pragma unroll
        for (int it = 0; it < 8; ++it) {
            const int s = cg * 8 + it;
            if (s + 2 < 32) {
                const int s2 = s + 2, cg2 = s2 >> 3, it2 = s2 & 7;
#pragma unroll
                for (int ks = 0; ks < 2; ++ks)
#pragma unroll
                    for (int nf = 0; nf < 4; ++nf)
                        ring[s2 % 3][ks * 4 + nf] = *reinterpret_cast<const bf16x8*>(
                            Wb + cg2 * 32768 + nf * 8192 + it2 * 1024 + ks * 512);
            }
            __builtin_amdgcn_sched_barrier(0);
            bf16x8 a[2][4];
#pragma unroll
            for (int ks = 0; ks < 2; ++ks)
#pragma unroll
                for (int mf = 0; mf < 4; ++mf) {
                    int row = mf * 16 + lr;
                    int kc = it * 8 + ks * 4 + lg;
                    a[ks][mf] = *reinterpret_cast<const bf16x8*>(
                        sAb + (size_t)(row * 64 + (kc ^ (row & 7))) * 16);
                }
#pragma unroll
            for (int ks = 0; ks < 2; ++ks)
#pragma unroll
                for (int nf = 0; nf < 4; ++nf)
#pragma unroll
                    for (int mf = 0; mf < 4; ++mf)
                        acc[mf][nf] = __builtin_amdgcn_mfma_f32_16x16x32_bf16(
                            a[ks][mf], ring[s % 3][ks * 4 + nf], acc[mf][nf], 0, 0, 0);
        }
        int colbase = w * 256 + cg * 64;
#pragma unroll
        for (int nf = 0; nf < 4; ++nf) {
            float bv = bp[(colbase + nf * 16 + lr) & 255];
#pragma unroll
            for (int mf = 0; mf < 4; ++mf)
#pragma unroll
                for (int r = 0; r < 4; ++r) {
                    float v = acc[mf][nf][r] + bv;
                    v = v > 0.f ? v : 0.f;
                    myT[(mf * 16 + lg * 4 + r) * 20 + lr] = f2bf(v);
                }
#pragma unroll
            for (int i = 0; i < 2; ++i) {
                int idx = i * 64 + l;
                int row = idx >> 1, half = idx & 1;
                ushort8 o = *reinterpret_cast<const ushort8*>(myT + row * 20 + half * 8);
                *reinterpret_cast<ushort8*>(
                    hid + (size_t)(mt * 64 + row) * 1024 + colbase + nf * 16 + half * 8) = o;
            }
        }
    }
}

// ---------------------------------------------------------------------------
// DIAGNOSTIC probes: same structure as k_l1, with operand streams ablated.
// KB=1: kill the per-step B global-load stream (reuse prologue ring[0]).
// KA=1: kill the per-step A ds_read stream (reuse one batch).
// Output written to hid (garbage) — production k_l1 overwrites it after.
// ---------------------------------------------------------------------------
template<int KB, int KA>
__global__ __launch_bounds__(256) void k_probe(
    const float* __restrict__ S, const ushort* __restrict__ W1p,
    ushort* __restrict__ hid, int m0)
{
    __shared__ ushort sA[64 * 512];
    __shared__ ushort sT[4][64 * 20];
    char* sAb = reinterpret_cast<char*>(sA);

    int tid = threadIdx.x, l = tid & 63, w = tid >> 6;
    int lr = l & 15, lg = l >> 4;
    int mt = blockIdx.x;
    const float* Srow = S + (size_t)(m0 + mt * 64) * 512;
    const ushort* Wb = W1p + (size_t)w * 131072 + (size_t)l * 8;

    bf16x8 ring[3][8];
#pragma unroll
    for (int p = 0; p < 2; ++p)
#pragma unroll
        for (int ks = 0; ks < 2; ++ks)
#pragma unroll
            for (int nf = 0; nf < 4; ++nf)
                ring[p][ks * 4 + nf] = *reinterpret_cast<const bf16x8*>(
                    Wb + nf * 8192 + p * 1024 + ks * 512);

#pragma unroll
    for (int i = 0; i < 16; ++i) {
        int c = i * 256 + tid;
        int row = c >> 6, kc = c & 63;
        const float4* g = reinterpret_cast<const float4*>(Srow + (size_t)row * 512 + kc * 8);
        float4 fa = g[0], fb = g[1];
        uint4 o;
        o.x = cvtpk(fa.x, fa.y); o.y = cvtpk(fa.z, fa.w);
        o.z = cvtpk(fb.x, fb.y); o.w = cvtpk(fb.z, fb.w);
        *reinterpret_cast<uint4*>(sAb + (size_t)(row * 64 + (kc ^ (row & 7))) * 16) = o;
    }
    __syncthreads();

    // pre-loaded A batch for KA=1
    bf16x8 aPre[2][4];
#pragma unroll
    for (int ks = 0; ks < 2; ++ks)
#pragma unroll
        for (int mf = 0; mf < 4; ++mf) {
            int row = mf * 16 + lr;
            aPre[ks][mf] = *reinterpret_cast<const bf16x8*>(
                sAb + (size_t)(row * 64 + ((ks * 4 + lg) ^ (row & 7))) * 16);
        }

#pragma unroll
    for (int cg = 0; cg < 4; ++cg) {
        f32x4 acc[4][4] = {{{0.f}}};
#pragma unroll
        for (int it = 0; it < 8; ++it) {
            const int s = cg * 8 + it;
            if constexpr (!KB) {
                if (s + 2 < 32) {
                    const int s2 = s + 2, cg2 = s2 >> 3, it2 = s2 & 7;
#pragma unroll
                    for (int ks = 0; ks < 2; ++ks)
#pragma unroll
                        for (int nf = 0; nf < 4; ++nf)
                            ring[s2 % 3][ks * 4 + nf] = *reinterpret_cast<const bf16x8*>(
                                Wb + cg2 * 32768 + nf * 8192 + it2 * 1024 + ks * 512);
                }
            }
            __builtin_amdgcn_sched_barrier(0);
            bf16x8 a[2][4];
            if constexpr (!KA) {
#pragma unroll
                for (int ks = 0; ks < 2; ++ks)
#pragma unroll
                    for (int mf = 0; mf < 4; ++mf) {
                        int row = mf * 16 + lr;
                        int kc = it * 8 + ks * 4 + lg;
                        a[ks][mf] = *reinterpret_cast<const bf16x8*>(
                            sAb + (size_t)(row * 64 + (kc ^ (row & 7))) * 16);
                    }
            } else {
#pragma unroll
                for (int ks = 0; ks < 2; ++ks)
#pragma unroll
                    for (int mf = 0; mf < 4; ++mf) a[ks][mf] = aPre[ks][mf];
            }
#pragma unroll
            for (int ks = 0; ks < 2; ++ks)
#pragma unroll
                for (int nf = 0; nf < 4; ++nf)
#pragma unroll
                    for (int mf = 0; mf < 4; ++mf)
                        acc[mf][nf] = __builtin_amdgcn_mfma_f32_16x16x32_bf16(
                            a[ks][mf], KB ? ring[0][ks * 4 + nf] : ring[s % 3][ks * 4 + nf],
                            acc[mf][nf], 0, 0, 0);
        }
        // epilogue (keeps acc live; hid garbage, overwritten by production k_l1)
        int colbase = w * 256 + cg * 64;
#pragma unroll
        for (int nf = 0; nf < 4; ++nf) {
#pragma unroll
            for (int mf = 0; mf < 4; ++mf)
#pragma unroll
                for (int r = 0; r < 4; ++r) {
                    float v = acc[mf][nf][r];
                    v = v > 0.f ? v : 0.f;
                    myT_write: ;
                    sT[w][(mf * 16 + lg * 4 + r) * 20 + lr] = f2bf(v);
                }
#pragma unroll
            for (int i = 0; i < 2; ++i) {
                int idx = i * 64 + l;
                int row = idx >> 1, half = idx & 1;
                ushort8 o = *reinterpret_cast<const ushort8*>(sT[w] + row * 20 + half * 8);
                *reinterpret_cast<ushort8*>(
                    hid + (size_t)(mt * 64 + row) * 1024 + colbase + nf * 16 + half * 8) = o;
            }
        }
    }
}

// ---------------------------------------------------------------------------
// Layer-2 (4 block GEMMs via MFMA) + mixer, fused. 32 samples / wg. (unchanged)
// ---------------------------------------------------------------------------
__global__ __launch_bounds__(256) void k_l2mix(
    const ushort* __restrict__ hid, const ushort* __restrict__ W2p,
    const float* __restrict__ bw1, const float* __restrict__ bb1,
    const float* __restrict__ bw2, const float* __restrict__ bb2,
    const float* __restrict__ q, float* __restrict__ out, int m0)
{
    __shared__ float sO[32 * 336];
    int tid = threadIdx.x, l = tid & 63, w = tid >> 6;
    int lr = l & 15, lg = l >> 4;
    int sb = blockIdx.x * 32;

    const int fs[5] = {0, 6, 12, 17, 21};
    int jloaded = -1;
    bf16x8 a[2][8];
    for (int f = fs[w]; f < fs[w + 1]; ++f) {
        int j = (f < 12) ? 0 : (f < 16) ? 1 : (f < 20) ? 2 : 3;
        if (j != jloaded) {
#pragma unroll
            for (int mf = 0; mf < 2; ++mf)
#pragma unroll
                for (int ks = 0; ks < 8; ++ks)
                    a[mf][ks] = *reinterpret_cast<const bf16x8*>(
                        hid + (size_t)(sb + mf * 16 + lr) * 1024 + j * 256 + ks * 32 + lg * 8);
            jloaded = j;
        }
        f32x4 acc[2] = {};
#pragma unroll
        for (int ks = 0; ks < 8; ++ks) {
            bf16x8 b = *reinterpret_cast<const bf16x8*>(W2p + ((size_t)(f * 8 + ks) * 64 + l) * 8);
            acc[0] = __builtin_amdgcn_mfma_f32_16x16x32_bf16(a[0][ks], b, acc[0], 0, 0, 0);
            acc[1] = __builtin_amdgcn_mfma_f32_16x16x32_bf16(a[1][ks], b, acc[1], 0, 0, 0);
        }
        int colg = f * 16 + lr;
        float bv = 0.f; bool doabs = false;
        if (colg < 192)       { bv = bw1[colg];       doabs = true; }
        else if (colg < 256)  { bv = bb1[colg - 192]; doabs = false; }
        else if (colg < 320)  { bv = bw2[colg - 256]; doabs = true; }
        else if (colg == 320) { bv = bb2[0];          doabs = false; }
#pragma unroll
        for (int mf = 0; mf < 2; ++mf)
#pragma unroll
            for (int r = 0; r < 4; ++r) {
                float v = acc[mf][r] + bv;
                if (doabs) v = fabsf(v);
                sO[(mf * 16 + lg * 4 + r) * 336 + colg] = v;
            }
    }
    __syncthreads();

    int sm = tid >> 3, oct = tid & 7;
    const float* qs = q + (size_t)(m0 + sb + sm) * 3;
    float q0 = qs[0], q1 = qs[1], q2 = qs[2];
    const float* ob = sO + sm * 336;
    float res[3];
#pragma unroll
    for (int n = 0; n < 3; ++n) {
        float qa, qb, qc;
        if (n == 0)      { qa = q0; qb = q1; qc = q2; }
        else if (n == 1) { qa = q1; qb = q0; qc = q2; }
        else             { qa = q2; qb = q0; qc = q1; }
        float accm = 0.f;
#pragma unroll
        for (int hh = 0; hh < 8; ++hh) {
            int hc = oct * 8 + hh;
            float hv = ob[192 + hc] + qa * ob[hc] + qb * ob[64 + hc] + qc * ob[128 + hc];
            float ev = hv > 0.f ? hv : expm1f(hv);
            accm += ev * ob[256 + hc];
        }
        accm += __shfl_xor(accm, 1);
        accm += __shfl_xor(accm, 2);
        accm += __shfl_xor(accm, 4);
        res[n] = accm;
    }
    if (oct == 0) {
        float b2v = ob[320];
        float* op = out + (size_t)(m0 + sb + sm) * 3;
        op[0] = res[0] + b2v;
        op[1] = res[1] + b2v;
        op[2] = res[2] + b2v;
    }
}

extern "C" void kernel_launch(void* const* d_in, const int* in_sizes, int n_in,
                              void* d_out, int out_size, void* d_ws, size_t ws_size,
                              hipStream_t stream)
{
    const float* q      = (const float*)d_in[0];
    const float* S      = (const float*)d_in[1];
    const float* hw1_W1 = (const float*)d_in[2];
    const float* hw1_b1 = (const float*)d_in[3];
    const float* hw1_W2 = (const float*)d_in[4];
    const float* hw1_b2 = (const float*)d_in[5];
    const float* hb1_W1 = (const float*)d_in[6];
    const float* hb1_b1 = (const float*)d_in[7];
    const float* hb1_W2 = (const float*)d_in[8];
    const float* hb1_b2 = (const float*)d_in[9];
    const float* hw2_W1 = (const float*)d_in[10];
    const float* hw2_b1 = (const float*)d_in[11];
    const float* hw2_W2 = (const float*)d_in[12];
    const float* hw2_b2 = (const float*)d_in[13];
    const float* hb2_W1 = (const float*)d_in[14];
    const float* hb2_b1 = (const float*)d_in[15];
    const float* hb2_W2 = (const float*)d_in[16];
    const float* hb2_b2 = (const float*)d_in[17];

    int TB = in_sizes[1] / 512;

    ushort* W1p = (ushort*)d_ws;
    ushort* W2p = W1p + (size_t)65536 * 8;
    ushort* hid = W2p + (size_t)10752 * 8;
    size_t used = (size_t)(65536 + 10752) * 16;
    size_t hid_cap = (ws_size > used) ? (ws_size - used) : 0;
    long long max_chunk = (long long)(hid_cap / 2048);
    max_chunk &= ~127LL;
    if (max_chunk > TB) max_chunk = TB;
    if (max_chunk < 128) max_chunk = 128;

    k_pack<<<dim3(298), dim3(256), 0, stream>>>(
        hw1_W1, hb1_W1, hw2_W1, hb2_W1,
        hw1_W2, hb1_W2, hw2_W2, hb2_W2, W1p, W2p);

    // ---- diagnostic probes (hid garbage, overwritten by production k_l1) ----
    int pgrid = (int)((max_chunk < TB ? max_chunk : TB) / 64);
    k_probe<1, 1><<<dim3(pgrid), dim3(256), 0, stream>>>(S, W1p, hid, 0);  // MFMA only
    k_probe<1, 0><<<dim3(pgrid), dim3(256), 0, stream>>>(S, W1p, hid, 0);  // +A stream
    k_probe<0, 1><<<dim3(pgrid), dim3(256), 0, stream>>>(S, W1p, hid, 0);  // +B stream

    for (int m0 = 0; m0 < TB; m0 += (int)max_chunk) {
        int mc = TB - m0;
        if (mc > max_chunk) mc = (int)max_chunk;
        k_l1<<<dim3(mc / 64), dim3(256), 0, stream>>>(
            S, W1p, hw1_b1, hb1_b1, hw2_b1, hb2_b1, hid, m0);
        k_l2mix<<<dim3(mc / 32), dim3(256), 0, stream>>>(
            hid, W2p, hw1_b2, hb1_b2, hw2_b2, hb2_b2, q, (float*)d_out, m0);
    }
}

// Round 11
// 278.012 us; speedup vs baseline: 1.4217x; 1.4217x over previous
//
#include <hip/hip_runtime.h>
#include <hip/hip_bf16.h>

typedef __attribute__((ext_vector_type(8))) __bf16 bf16x8;
typedef __attribute__((ext_vector_type(4))) float f32x4;
typedef __attribute__((ext_vector_type(8))) unsigned short ushort8;
typedef unsigned short ushort;

__device__ __forceinline__ ushort f2bf(float f) {
    unsigned u = __builtin_bit_cast(unsigned, f);
    unsigned r = (u + 0x7fffu + ((u >> 16) & 1u)) >> 16;
    return (ushort)r;
}

__device__ __forceinline__ unsigned cvtpk(float a, float b) {
    unsigned r;
    asm("v_cvt_pk_bf16_f32 %0, %1, %2" : "=v"(r) : "v"(a), "v"(b));
    return r;
}

// ---------------------------------------------------------------------------
// Pack layer-1 weights (4x [512,256] fp32) and layer-2 weights into bf16
// MFMA-B-fragment order in ws.
// W1p ushort offset = ((n16*16 + ksg)*64 + l)*8, n16 = j*16 + colfrag,
// element e: B[k = ksg*32 + (l>>4)*8 + e][col = (n16&15)*16 + (l&15)] of hyp j.
// ---------------------------------------------------------------------------
__global__ __launch_bounds__(256) void k_pack(
    const float* __restrict__ w1a, const float* __restrict__ w1b,
    const float* __restrict__ w1c, const float* __restrict__ w1d,
    const float* __restrict__ w2a, const float* __restrict__ w2b,
    const float* __restrict__ w2c, const float* __restrict__ w2d,
    ushort* __restrict__ W1p, ushort* __restrict__ W2p)
{
    int c = blockIdx.x * 256 + threadIdx.x;
    if (c < 65536) {
        int l = c & 63, ks = (c >> 6) & 15, n16 = c >> 10;
        int j = n16 >> 4;
        int col = (n16 & 15) * 16 + (l & 15);
        int kb = ks * 32 + (l >> 4) * 8;
        const float* W = (j == 0) ? w1a : (j == 1) ? w1b : (j == 2) ? w1c : w1d;
        ushort8 o;
#pragma unroll
        for (int e = 0; e < 8; ++e) o[e] = f2bf(W[(size_t)(kb + e) * 256 + col]);
        *reinterpret_cast<ushort8*>(W1p + (size_t)c * 8) = o;
    } else if (c < 65536 + 10752) {
        int cc = c - 65536;
        int l = cc & 63, ks = (cc >> 6) & 7, f = cc >> 9;
        int colg = f * 16 + (l & 15);
        int kb = ks * 32 + (l >> 4) * 8;
        const float* W = nullptr; int lc = 0, ncols = 1;
        if (colg < 192)        { W = w2a; lc = colg;       ncols = 192; }
        else if (colg < 256)   { W = w2b; lc = colg - 192; ncols = 64; }
        else if (colg < 320)   { W = w2c; lc = colg - 256; ncols = 64; }
        else if (colg == 320)  { W = w2d; lc = 0;          ncols = 1; }
        ushort8 o;
#pragma unroll
        for (int e = 0; e < 8; ++e)
            o[e] = W ? f2bf(W[(size_t)(kb + e) * ncols + lc]) : (ushort)0;
        *reinterpret_cast<ushort8*>(W2p + (size_t)cc * 8) = o;
    }
}

// ---------------------------------------------------------------------------
// Layer-1 GEMM v8: block = 128 rows x 512 cols (ct half of 1024), 512 thr =
// 8 waves; wave w owns cols [ct*512 + w*64, +64), ALL 128 rows: acc[8][4]
// = 128 VGPR. Each 1 KB B-frag feeds 8 MFMAs (128 B/MFMA vs 256 before)
// => B L2-BW demand at full MFMA rate ~26 B/cyc/CU, under the ~56 supply.
// S read 2x total (ct=0 sweep loads L3, ct=1 hits L3). K staged in 2 chunks
// of 256 into one 64 KB swizzled LDS buffer -> 2 blocks/CU, 16 waves/CU.
// Dist-2 B register ring + sched_barrier (proven R7). Epilogue aliases sA.
// ---------------------------------------------------------------------------
__global__ __launch_bounds__(512, 1) void k_l1(
    const float* __restrict__ S, const ushort* __restrict__ W1p,
    const float* __restrict__ b0, const float* __restrict__ b1,
    const float* __restrict__ b2, const float* __restrict__ b3,
    ushort* __restrict__ hid, int m0)
{
    __shared__ ushort sA[128 * 256];  // 64 KB, 16B-granule swizzle g^(row&7)
    char* sAb = reinterpret_cast<char*>(sA);

    int tid = threadIdx.x, l = tid & 63, w = tid >> 6;  // w in 0..7
    int lr = l & 15, lg = l >> 4;
    int mt = blockIdx.x, ct = blockIdx.y;
    const float* Srow = S + (size_t)(m0 + mt * 128) * 512;

    f32x4 acc[8][4] = {};
    bf16x8 ring[3][8];

    // B-frag issue for step s (s = chunk*4 + it): ksg = s*2 + ks
#define ISSUE_B(s, buf)                                                        \
    {                                                                          \
        _Pragma("unroll")                                                      \
        for (int ks = 0; ks < 2; ++ks)                                         \
            _Pragma("unroll")                                                  \
            for (int nf = 0; nf < 4; ++nf) {                                   \
                int n16 = ct * 32 + w * 4 + nf;                                \
                int ksg = (s) * 2 + ks;                                        \
                ring[buf][ks * 4 + nf] = *reinterpret_cast<const bf16x8*>(     \
                    W1p + ((size_t)(n16 * 16 + ksg) * 64 + l) * 8);            \
            }                                                                  \
    }

    ISSUE_B(0, 0)
    ISSUE_B(1, 1)

    // ---- stage chunk 0: S[128 rows][k 0..256) fp32 -> bf16, swizzled
#pragma unroll
    for (int i = 0; i < 8; ++i) {
        int idx = i * 512 + tid;
        int row = idx >> 5, g = idx & 31;
        const float4* gp = reinterpret_cast<const float4*>(
            Srow + (size_t)row * 512 + g * 8);
        float4 fa = gp[0], fb = gp[1];
        uint4 o;
        o.x = cvtpk(fa.x, fa.y); o.y = cvtpk(fa.z, fa.w);
        o.z = cvtpk(fb.x, fb.y); o.w = cvtpk(fb.z, fb.w);
        *reinterpret_cast<uint4*>(sAb + (size_t)(row * 32 + (g ^ (row & 7))) * 16) = o;
    }
    __syncthreads();

#pragma unroll
    for (int s = 0; s < 8; ++s) {
        if (s == 4) {
            __syncthreads();  // all waves done reading chunk 0
#pragma unroll
            for (int i = 0; i < 8; ++i) {
                int idx = i * 512 + tid;
                int row = idx >> 5, g = idx & 31;
                const float4* gp = reinterpret_cast<const float4*>(
                    Srow + (size_t)row * 512 + 256 + g * 8);
                float4 fa = gp[0], fb = gp[1];
                uint4 o;
                o.x = cvtpk(fa.x, fa.y); o.y = cvtpk(fa.z, fa.w);
                o.z = cvtpk(fb.x, fb.y); o.w = cvtpk(fb.z, fb.w);
                *reinterpret_cast<uint4*>(
                    sAb + (size_t)(row * 32 + (g ^ (row & 7))) * 16) = o;
            }
            __syncthreads();
        }
        if (s + 2 < 8) ISSUE_B(s + 2, (s + 2) % 3)
        __builtin_amdgcn_sched_barrier(0);  // pin B-issue at region top
        // ---- A fragments: 16 ds_read_b128 (8 mf x 2 ks), reused by 4 nf
        bf16x8 a[2][8];
#pragma unroll
        for (int ks = 0; ks < 2; ++ks)
#pragma unroll
            for (int mf = 0; mf < 8; ++mf) {
                int row = mf * 16 + lr;
                int g = (s & 3) * 8 + ks * 4 + lg;
                a[ks][mf] = *reinterpret_cast<const bf16x8*>(
                    sAb + (size_t)(row * 32 + (g ^ (row & 7))) * 16);
            }
        // ---- 64 MFMA consuming ring[s%3] (issued 2 steps ago)
#pragma unroll
        for (int ks = 0; ks < 2; ++ks)
#pragma unroll
            for (int nf = 0; nf < 4; ++nf)
#pragma unroll
                for (int mf = 0; mf < 8; ++mf)
                    acc[mf][nf] = __builtin_amdgcn_mfma_f32_16x16x32_bf16(
                        a[ks][mf], ring[s % 3][ks * 4 + nf], acc[mf][nf], 0, 0, 0);
    }
#undef ISSUE_B

    __syncthreads();  // sA dead; alias per-wave transpose scratch

    int cb = ct * 512 + w * 64;
    int j = cb >> 8;
    const float* bp = (j == 0) ? b0 : (j == 1) ? b1 : (j == 2) ? b2 : b3;
    ushort* myT = sA + (size_t)w * 2560;  // [128][20] u16 = 5 KB per wave

#pragma unroll
    for (int nf = 0; nf < 4; ++nf) {
        float bv = bp[(cb + nf * 16 + lr) & 255];
#pragma unroll
        for (int mf = 0; mf < 8; ++mf)
#pragma unroll
            for (int r = 0; r < 4; ++r) {
                float v = acc[mf][nf][r] + bv;
                v = v > 0.f ? v : 0.f;
                myT[(mf * 16 + lg * 4 + r) * 20 + lr] = f2bf(v);
            }
#pragma unroll
        for (int i = 0; i < 4; ++i) {
            int idx = i * 64 + l;
            int row = idx >> 1, half = idx & 1;
            ushort8 o = *reinterpret_cast<const ushort8*>(myT + row * 20 + half * 8);
            *reinterpret_cast<ushort8*>(
                hid + (size_t)(mt * 128 + row) * 1024 + cb + nf * 16 + half * 8) = o;
        }
    }
}

// ---------------------------------------------------------------------------
// Layer-2 (4 block GEMMs via MFMA) + mixer, fused. 32 samples / wg. (unchanged)
// ---------------------------------------------------------------------------
__global__ __launch_bounds__(256) void k_l2mix(
    const ushort* __restrict__ hid, const ushort* __restrict__ W2p,
    const float* __restrict__ bw1, const float* __restrict__ bb1,
    const float* __restrict__ bw2, const float* __restrict__ bb2,
    const float* __restrict__ q, float* __restrict__ out, int m0)
{
    __shared__ float sO[32 * 336];
    int tid = threadIdx.x, l = tid & 63, w = tid >> 6;
    int lr = l & 15, lg = l >> 4;
    int sb = blockIdx.x * 32;

    const int fs[5] = {0, 6, 12, 17, 21};
    int jloaded = -1;
    bf16x8 a[2][8];
    for (int f = fs[w]; f < fs[w + 1]; ++f) {
        int j = (f < 12) ? 0 : (f < 16) ? 1 : (f < 20) ? 2 : 3;
        if (j != jloaded) {
#pragma unroll
            for (int mf = 0; mf < 2; ++mf)
#pragma unroll
                for (int ks = 0; ks < 8; ++ks)
                    a[mf][ks] = *reinterpret_cast<const bf16x8*>(
                        hid + (size_t)(sb + mf * 16 + lr) * 1024 + j * 256 + ks * 32 + lg * 8);
            jloaded = j;
        }
        f32x4 acc[2] = {};
#pragma unroll
        for (int ks = 0; ks < 8; ++ks) {
            bf16x8 b = *reinterpret_cast<const bf16x8*>(W2p + ((size_t)(f * 8 + ks) * 64 + l) * 8);
            acc[0] = __builtin_amdgcn_mfma_f32_16x16x32_bf16(a[0][ks], b, acc[0], 0, 0, 0);
            acc[1] = __builtin_amdgcn_mfma_f32_16x16x32_bf16(a[1][ks], b, acc[1], 0, 0, 0);
        }
        int colg = f * 16 + lr;
        float bv = 0.f; bool doabs = false;
        if (colg < 192)       { bv = bw1[colg];       doabs = true; }
        else if (colg < 256)  { bv = bb1[colg - 192]; doabs = false; }
        else if (colg < 320)  { bv = bw2[colg - 256]; doabs = true; }
        else if (colg == 320) { bv = bb2[0];          doabs = false; }
#pragma unroll
        for (int mf = 0; mf < 2; ++mf)
#pragma unroll
            for (int r = 0; r < 4; ++r) {
                float v = acc[mf][r] + bv;
                if (doabs) v = fabsf(v);
                sO[(mf * 16 + lg * 4 + r) * 336 + colg] = v;
            }
    }
    __syncthreads();

    int sm = tid >> 3, oct = tid & 7;
    const float* qs = q + (size_t)(m0 + sb + sm) * 3;
    float q0 = qs[0], q1 = qs[1], q2 = qs[2];
    const float* ob = sO + sm * 336;
    float res[3];
#pragma unroll
    for (int n = 0; n < 3; ++n) {
        float qa, qb, qc;
        if (n == 0)      { qa = q0; qb = q1; qc = q2; }
        else if (n == 1) { qa = q1; qb = q0; qc = q2; }
        else             { qa = q2; qb = q0; qc = q1; }
        float accm = 0.f;
#pragma unroll
        for (int hh = 0; hh < 8; ++hh) {
            int hc = oct * 8 + hh;
            float hv = ob[192 + hc] + qa * ob[hc] + qb * ob[64 + hc] + qc * ob[128 + hc];
            float ev = hv > 0.f ? hv : expm1f(hv);
            accm += ev * ob[256 + hc];
        }
        accm += __shfl_xor(accm, 1);
        accm += __shfl_xor(accm, 2);
        accm += __shfl_xor(accm, 4);
        res[n] = accm;
    }
    if (oct == 0) {
        float b2v = ob[320];
        float* op = out + (size_t)(m0 + sb + sm) * 3;
        op[0] = res[0] + b2v;
        op[1] = res[1] + b2v;
        op[2] = res[2] + b2v;
    }
}

extern "C" void kernel_launch(void* const* d_in, const int* in_sizes, int n_in,
                              void* d_out, int out_size, void* d_ws, size_t ws_size,
                              hipStream_t stream)
{
    const float* q      = (const float*)d_in[0];
    const float* S      = (const float*)d_in[1];
    const float* hw1_W1 = (const float*)d_in[2];
    const float* hw1_b1 = (const float*)d_in[3];
    const float* hw1_W2 = (const float*)d_in[4];
    const float* hw1_b2 = (const float*)d_in[5];
    const float* hb1_W1 = (const float*)d_in[6];
    const float* hb1_b1 = (const float*)d_in[7];
    const float* hb1_W2 = (const float*)d_in[8];
    const float* hb1_b2 = (const float*)d_in[9];
    const float* hw2_W1 = (const float*)d_in[10];
    const float* hw2_b1 = (const float*)d_in[11];
    const float* hw2_W2 = (const float*)d_in[12];
    const float* hw2_b2 = (const float*)d_in[13];
    const float* hb2_W1 = (const float*)d_in[14];
    const float* hb2_b1 = (const float*)d_in[15];
    const float* hb2_W2 = (const float*)d_in[16];
    const float* hb2_b2 = (const float*)d_in[17];

    int TB = in_sizes[1] / 512;

    ushort* W1p = (ushort*)d_ws;
    ushort* W2p = W1p + (size_t)65536 * 8;
    ushort* hid = W2p + (size_t)10752 * 8;
    size_t used = (size_t)(65536 + 10752) * 16;
    size_t hid_cap = (ws_size > used) ? (ws_size - used) : 0;
    long long max_chunk = (long long)(hid_cap / 2048);
    max_chunk &= ~127LL;
    if (max_chunk > TB) max_chunk = TB;
    if (max_chunk < 128) max_chunk = 128;

    k_pack<<<dim3(298), dim3(256), 0, stream>>>(
        hw1_W1, hb1_W1, hw2_W1, hb2_W1,
        hw1_W2, hb1_W2, hw2_W2, hb2_W2, W1p, W2p);

    for (int m0 = 0; m0 < TB; m0 += (int)max_chunk) {
        int mc = TB - m0;
        if (mc > max_chunk) mc = (int)max_chunk;
        k_l1<<<dim3(mc / 128, 2), dim3(512), 0, stream>>>(
            S, W1p, hw1_b1, hb1_b1, hw2_b1, hb2_b1, hid, m0);
        k_l2mix<<<dim3(mc / 32), dim3(256), 0, stream>>>(
            hid, W2p, hw1_b2, hb1_b2, hw2_b2, hb2_b2, q, (float*)d_out, m0);
    }
}

// Round 12
// 270.874 us; speedup vs baseline: 1.4591x; 1.0263x over previous
//
#include <hip/hip_runtime.h>
#include <hip/hip_bf16.h>

typedef __attribute__((ext_vector_type(8))) __bf16 bf16x8;
typedef __attribute__((ext_vector_type(4))) float f32x4;
typedef __attribute__((ext_vector_type(8))) unsigned short ushort8;
typedef unsigned short ushort;

__device__ __forceinline__ ushort f2bf(float f) {
    unsigned u = __builtin_bit_cast(unsigned, f);
    unsigned r = (u + 0x7fffu + ((u >> 16) & 1u)) >> 16;
    return (ushort)r;
}

__device__ __forceinline__ unsigned cvtpk(float a, float b) {
    unsigned r;
    asm("v_cvt_pk_bf16_f32 %0, %1, %2" : "=v"(r) : "v"(a), "v"(b));
    return r;
}

// ---------------------------------------------------------------------------
// Pack layer-1 weights (4x [512,256] fp32) and layer-2 weights into bf16
// MFMA-B-fragment order in ws. (unchanged)
// W1p ushort offset = ((n16*16 + ksg)*64 + l)*8, n16 = j*16 + colfrag,
// element e: B[k = ksg*32 + (l>>4)*8 + e][col = (n16&15)*16 + (l&15)] of hyp j.
// ---------------------------------------------------------------------------
__global__ __launch_bounds__(256) void k_pack(
    const float* __restrict__ w1a, const float* __restrict__ w1b,
    const float* __restrict__ w1c, const float* __restrict__ w1d,
    const float* __restrict__ w2a, const float* __restrict__ w2b,
    const float* __restrict__ w2c, const float* __restrict__ w2d,
    ushort* __restrict__ W1p, ushort* __restrict__ W2p)
{
    int c = blockIdx.x * 256 + threadIdx.x;
    if (c < 65536) {
        int l = c & 63, ks = (c >> 6) & 15, n16 = c >> 10;
        int j = n16 >> 4;
        int col = (n16 & 15) * 16 + (l & 15);
        int kb = ks * 32 + (l >> 4) * 8;
        const float* W = (j == 0) ? w1a : (j == 1) ? w1b : (j == 2) ? w1c : w1d;
        ushort8 o;
#pragma unroll
        for (int e = 0; e < 8; ++e) o[e] = f2bf(W[(size_t)(kb + e) * 256 + col]);
        *reinterpret_cast<ushort8*>(W1p + (size_t)c * 8) = o;
    } else if (c < 65536 + 10752) {
        int cc = c - 65536;
        int l = cc & 63, ks = (cc >> 6) & 7, f = cc >> 9;
        int colg = f * 16 + (l & 15);
        int kb = ks * 32 + (l >> 4) * 8;
        const float* W = nullptr; int lc = 0, ncols = 1;
        if (colg < 192)        { W = w2a; lc = colg;       ncols = 192; }
        else if (colg < 256)   { W = w2b; lc = colg - 192; ncols = 64; }
        else if (colg < 320)   { W = w2c; lc = colg - 256; ncols = 64; }
        else if (colg == 320)  { W = w2d; lc = 0;          ncols = 1; }
        ushort8 o;
#pragma unroll
        for (int e = 0; e < 8; ++e)
            o[e] = W ? f2bf(W[(size_t)(kb + e) * ncols + lc]) : (ushort)0;
        *reinterpret_cast<ushort8*>(W2p + (size_t)cc * 8) = o;
    }
}

// ---------------------------------------------------------------------------
// Layer-1 GEMM v9: block = 128 rows x 256 cols (ct = hypernet j), 256 thr =
// 4 waves; wave w owns cols [ct*256 + w*64, +64) over ALL 128 rows.
// acc[8][4] = 128 AGPR; VGPR live set sized to the remaining 128:
// ring[3][4] = 48 (B at half-step K=32 granularity, dist-2 = one K-64 of
// cover), a[8] = 32 per half-step, ~30 misc. 2 waves/SIMD cap = 256 unified
// regs -> NO SPILL (R9/R11 both silently spilled here).
// Each 1 KB B-frag feeds 8 MFMAs -> 128 B/MFMA: B L2-demand ~26 B/cyc/CU at
// full MFMA rate (supply ~56). Grid bx = mt*4 + ct: the 4 ct-blocks of the
// same rows are dispatch-adjacent -> S from HBM ~once, rest L3.
// K staged in 2 chunks of 256 into one 64 KB swizzled LDS -> 2 blocks/CU.
// ---------------------------------------------------------------------------
__global__ __launch_bounds__(256, 2) void k_l1(
    const float* __restrict__ S, const ushort* __restrict__ W1p,
    const float* __restrict__ b0, const float* __restrict__ b1,
    const float* __restrict__ b2, const float* __restrict__ b3,
    ushort* __restrict__ hid, int m0)
{
    __shared__ ushort sA[128 * 256];  // 64 KB, 16B-granule swizzle g^(row&7)
    char* sAb = reinterpret_cast<char*>(sA);

    int tid = threadIdx.x, l = tid & 63, w = tid >> 6;  // w in 0..3
    int lr = l & 15, lg = l >> 4;
    int mt = blockIdx.x >> 2, ct = blockIdx.x & 3;
    const float* Srow = S + (size_t)(m0 + mt * 128) * 512;

    f32x4 acc[8][4] = {};
    bf16x8 ring[3][4];

    // B-frag issue for half-step h (ksg = h, K=32): 4 frags (nf 0..3)
#define ISSUE_B(h, buf)                                                        \
    {                                                                          \
        _Pragma("unroll")                                                      \
        for (int nf = 0; nf < 4; ++nf) {                                       \
            int n16 = ct * 16 + w * 4 + nf;                                    \
            ring[buf][nf] = *reinterpret_cast<const bf16x8*>(                  \
                W1p + ((size_t)(n16 * 16 + (h)) * 64 + l) * 8);                \
        }                                                                      \
    }

    ISSUE_B(0, 0)
    ISSUE_B(1, 1)

    // ---- stage chunk 0: S[128 rows][k 0..256) fp32 -> bf16, swizzled
#pragma unroll
    for (int i = 0; i < 16; ++i) {
        int idx = i * 256 + tid;
        int row = idx >> 5, g = idx & 31;
        const float4* gp = reinterpret_cast<const float4*>(
            Srow + (size_t)row * 512 + g * 8);
        float4 fa = gp[0], fb = gp[1];
        uint4 o;
        o.x = cvtpk(fa.x, fa.y); o.y = cvtpk(fa.z, fa.w);
        o.z = cvtpk(fb.x, fb.y); o.w = cvtpk(fb.z, fb.w);
        *reinterpret_cast<uint4*>(sAb + (size_t)(row * 32 + (g ^ (row & 7))) * 16) = o;
    }
    __syncthreads();

#pragma unroll
    for (int h = 0; h < 16; ++h) {  // half-steps: ksg = h, K=32 each
        if (h == 8) {
            __syncthreads();  // all waves done reading chunk 0
#pragma unroll
            for (int i = 0; i < 16; ++i) {
                int idx = i * 256 + tid;
                int row = idx >> 5, g = idx & 31;
                const float4* gp = reinterpret_cast<const float4*>(
                    Srow + (size_t)row * 512 + 256 + g * 8);
                float4 fa = gp[0], fb = gp[1];
                uint4 o;
                o.x = cvtpk(fa.x, fa.y); o.y = cvtpk(fa.z, fa.w);
                o.z = cvtpk(fb.x, fb.y); o.w = cvtpk(fb.z, fb.w);
                *reinterpret_cast<uint4*>(
                    sAb + (size_t)(row * 32 + (g ^ (row & 7))) * 16) = o;
            }
            __syncthreads();
        }
        if (h + 2 < 16) ISSUE_B(h + 2, (h + 2) % 3)
        __builtin_amdgcn_sched_barrier(0);  // pin B-issue at region top
        // ---- A fragments: 8 ds_read_b128, reused by the 4 nf
        bf16x8 a[8];
#pragma unroll
        for (int mf = 0; mf < 8; ++mf) {
            int row = mf * 16 + lr;
            int g = (h & 7) * 4 + lg;
            a[mf] = *reinterpret_cast<const bf16x8*>(
                sAb + (size_t)(row * 32 + (g ^ (row & 7))) * 16);
        }
        // ---- 32 MFMA consuming ring[h%3] (issued 2 half-steps ago)
#pragma unroll
        for (int nf = 0; nf < 4; ++nf)
#pragma unroll
            for (int mf = 0; mf < 8; ++mf)
                acc[mf][nf] = __builtin_amdgcn_mfma_f32_16x16x32_bf16(
                    a[mf], ring[h % 3][nf], acc[mf][nf], 0, 0, 0);
    }
#undef ISSUE_B

    __syncthreads();  // sA dead; alias per-wave transpose scratch

    int cb = ct * 256 + w * 64;
    const float* bp = (ct == 0) ? b0 : (ct == 1) ? b1 : (ct == 2) ? b2 : b3;
    ushort* myT = sA + (size_t)w * 2560;  // [128][20] u16 = 5 KB per wave

#pragma unroll
    for (int nf = 0; nf < 4; ++nf) {
        float bv = bp[(cb + nf * 16 + lr) & 255];
#pragma unroll
        for (int mf = 0; mf < 8; ++mf)
#pragma unroll
            for (int r = 0; r < 4; ++r) {
                float v = acc[mf][nf][r] + bv;
                v = v > 0.f ? v : 0.f;
                myT[(mf * 16 + lg * 4 + r) * 20 + lr] = f2bf(v);
            }
#pragma unroll
        for (int i = 0; i < 4; ++i) {
            int idx = i * 64 + l;
            int row = idx >> 1, half = idx & 1;
            ushort8 o = *reinterpret_cast<const ushort8*>(myT + row * 20 + half * 8);
            *reinterpret_cast<ushort8*>(
                hid + (size_t)(mt * 128 + row) * 1024 + cb + nf * 16 + half * 8) = o;
        }
    }
}

// ---------------------------------------------------------------------------
// Layer-2 (4 block GEMMs via MFMA) + mixer, fused. 32 samples / wg. (unchanged)
// ---------------------------------------------------------------------------
__global__ __launch_bounds__(256) void k_l2mix(
    const ushort* __restrict__ hid, const ushort* __restrict__ W2p,
    const float* __restrict__ bw1, const float* __restrict__ bb1,
    const float* __restrict__ bw2, const float* __restrict__ bb2,
    const float* __restrict__ q, float* __restrict__ out, int m0)
{
    __shared__ float sO[32 * 336];
    int tid = threadIdx.x, l = tid & 63, w = tid >> 6;
    int lr = l & 15, lg = l >> 4;
    int sb = blockIdx.x * 32;

    const int fs[5] = {0, 6, 12, 17, 21};
    int jloaded = -1;
    bf16x8 a[2][8];
    for (int f = fs[w]; f < fs[w + 1]; ++f) {
        int j = (f < 12) ? 0 : (f < 16) ? 1 : (f < 20) ? 2 : 3;
        if (j != jloaded) {
#pragma unroll
            for (int mf = 0; mf < 2; ++mf)
#pragma unroll
                for (int ks = 0; ks < 8; ++ks)
                    a[mf][ks] = *reinterpret_cast<const bf16x8*>(
                        hid + (size_t)(sb + mf * 16 + lr) * 1024 + j * 256 + ks * 32 + lg * 8);
            jloaded = j;
        }
        f32x4 acc[2] = {};
#pragma unroll
        for (int ks = 0; ks < 8; ++ks) {
            bf16x8 b = *reinterpret_cast<const bf16x8*>(W2p + ((size_t)(f * 8 + ks) * 64 + l) * 8);
            acc[0] = __builtin_amdgcn_mfma_f32_16x16x32_bf16(a[0][ks], b, acc[0], 0, 0, 0);
            acc[1] = __builtin_amdgcn_mfma_f32_16x16x32_bf16(a[1][ks], b, acc[1], 0, 0, 0);
        }
        int colg = f * 16 + lr;
        float bv = 0.f; bool doabs = false;
        if (colg < 192)       { bv = bw1[colg];       doabs = true; }
        else if (colg < 256)  { bv = bb1[colg - 192]; doabs = false; }
        else if (colg < 320)  { bv = bw2[colg - 256]; doabs = true; }
        else if (colg == 320) { bv = bb2[0];          doabs = false; }
#pragma unroll
        for (int mf = 0; mf < 2; ++mf)
#pragma unroll
            for (int r = 0; r < 4; ++r) {
                float v = acc[mf][r] + bv;
                if (doabs) v = fabsf(v);
                sO[(mf * 16 + lg * 4 + r) * 336 + colg] = v;
            }
    }
    __syncthreads();

    int sm = tid >> 3, oct = tid & 7;
    const float* qs = q + (size_t)(m0 + sb + sm) * 3;
    float q0 = qs[0], q1 = qs[1], q2 = qs[2];
    const float* ob = sO + sm * 336;
    float res[3];
#pragma unroll
    for (int n = 0; n < 3; ++n) {
        float qa, qb, qc;
        if (n == 0)      { qa = q0; qb = q1; qc = q2; }
        else if (n == 1) { qa = q1; qb = q0; qc = q2; }
        else             { qa = q2; qb = q0; qc = q1; }
        float accm = 0.f;
#pragma unroll
        for (int hh = 0; hh < 8; ++hh) {
            int hc = oct * 8 + hh;
            float hv = ob[192 + hc] + qa * ob[hc] + qb * ob[64 + hc] + qc * ob[128 + hc];
            float ev = hv > 0.f ? hv : expm1f(hv);
            accm += ev * ob[256 + hc];
        }
        accm += __shfl_xor(accm, 1);
        accm += __shfl_xor(accm, 2);
        accm += __shfl_xor(accm, 4);
        res[n] = accm;
    }
    if (oct == 0) {
        float b2v = ob[320];
        float* op = out + (size_t)(m0 + sb + sm) * 3;
        op[0] = res[0] + b2v;
        op[1] = res[1] + b2v;
        op[2] = res[2] + b2v;
    }
}

extern "C" void kernel_launch(void* const* d_in, const int* in_sizes, int n_in,
                              void* d_out, int out_size, void* d_ws, size_t ws_size,
                              hipStream_t stream)
{
    const float* q      = (const float*)d_in[0];
    const float* S      = (const float*)d_in[1];
    const float* hw1_W1 = (const float*)d_in[2];
    const float* hw1_b1 = (const float*)d_in[3];
    const float* hw1_W2 = (const float*)d_in[4];
    const float* hw1_b2 = (const float*)d_in[5];
    const float* hb1_W1 = (const float*)d_in[6];
    const float* hb1_b1 = (const float*)d_in[7];
    const float* hb1_W2 = (const float*)d_in[8];
    const float* hb1_b2 = (const float*)d_in[9];
    const float* hw2_W1 = (const float*)d_in[10];
    const float* hw2_b1 = (const float*)d_in[11];
    const float* hw2_W2 = (const float*)d_in[12];
    const float* hw2_b2 = (const float*)d_in[13];
    const float* hb2_W1 = (const float*)d_in[14];
    const float* hb2_b1 = (const float*)d_in[15];
    const float* hb2_W2 = (const float*)d_in[16];
    const float* hb2_b2 = (const float*)d_in[17];

    int TB = in_sizes[1] / 512;

    ushort* W1p = (ushort*)d_ws;
    ushort* W2p = W1p + (size_t)65536 * 8;
    ushort* hid = W2p + (size_t)10752 * 8;
    size_t used = (size_t)(65536 + 10752) * 16;
    size_t hid_cap = (ws_size > used) ? (ws_size - used) : 0;
    long long max_chunk = (long long)(hid_cap / 2048);
    max_chunk &= ~127LL;
    if (max_chunk > TB) max_chunk = TB;
    if (max_chunk < 128) max_chunk = 128;

    k_pack<<<dim3(298), dim3(256), 0, stream>>>(
        hw1_W1, hb1_W1, hw2_W1, hb2_W1,
        hw1_W2, hb1_W2, hw2_W2, hb2_W2, W1p, W2p);

    for (int m0 = 0; m0 < TB; m0 += (int)max_chunk) {
        int mc = TB - m0;
        if (mc > max_chunk) mc = (int)max_chunk;
        k_l1<<<dim3((mc / 128) * 4), dim3(256), 0, stream>>>(
            S, W1p, hw1_b1, hb1_b1, hw2_b1, hb2_b1, hid, m0);
        k_l2mix<<<dim3(mc / 32), dim3(256), 0, stream>>>(
            hid, W2p, hw1_b2, hb1_b2, hw2_b2, hb2_b2, q, (float*)d_out, m0);
    }
}

// Round 13
// 269.073 us; speedup vs baseline: 1.4689x; 1.0067x over previous
//
#include <hip/hip_runtime.h>
#include <hip/hip_bf16.h>

typedef __attribute__((ext_vector_type(8))) __bf16 bf16x8;
typedef __attribute__((ext_vector_type(4))) float f32x4;
typedef __attribute__((ext_vector_type(8))) unsigned short ushort8;
typedef unsigned short ushort;

__device__ __forceinline__ ushort f2bf(float f) {
    unsigned u = __builtin_bit_cast(unsigned, f);
    unsigned r = (u + 0x7fffu + ((u >> 16) & 1u)) >> 16;
    return (ushort)r;
}

__device__ __forceinline__ unsigned cvtpk(float a, float b) {
    unsigned r;
    asm("v_cvt_pk_bf16_f32 %0, %1, %2" : "=v"(r) : "v"(a), "v"(b));
    return r;
}

// ---------------------------------------------------------------------------
// Pack layer-1 weights (4x [512,256] fp32) and layer-2 weights into bf16
// MFMA-B-fragment order in ws. (unchanged)
// W1p ushort offset = ((n16*16 + ksg)*64 + l)*8, n16 = j*16 + colfrag,
// element e: B[k = ksg*32 + (l>>4)*8 + e][col = (n16&15)*16 + (l&15)] of hyp j.
// ---------------------------------------------------------------------------
__global__ __launch_bounds__(256) void k_pack(
    const float* __restrict__ w1a, const float* __restrict__ w1b,
    const float* __restrict__ w1c, const float* __restrict__ w1d,
    const float* __restrict__ w2a, const float* __restrict__ w2b,
    const float* __restrict__ w2c, const float* __restrict__ w2d,
    ushort* __restrict__ W1p, ushort* __restrict__ W2p)
{
    int c = blockIdx.x * 256 + threadIdx.x;
    if (c < 65536) {
        int l = c & 63, ks = (c >> 6) & 15, n16 = c >> 10;
        int j = n16 >> 4;
        int col = (n16 & 15) * 16 + (l & 15);
        int kb = ks * 32 + (l >> 4) * 8;
        const float* W = (j == 0) ? w1a : (j == 1) ? w1b : (j == 2) ? w1c : w1d;
        ushort8 o;
#pragma unroll
        for (int e = 0; e < 8; ++e) o[e] = f2bf(W[(size_t)(kb + e) * 256 + col]);
        *reinterpret_cast<ushort8*>(W1p + (size_t)c * 8) = o;
    } else if (c < 65536 + 10752) {
        int cc = c - 65536;
        int l = cc & 63, ks = (cc >> 6) & 7, f = cc >> 9;
        int colg = f * 16 + (l & 15);
        int kb = ks * 32 + (l >> 4) * 8;
        const float* W = nullptr; int lc = 0, ncols = 1;
        if (colg < 192)        { W = w2a; lc = colg;       ncols = 192; }
        else if (colg < 256)   { W = w2b; lc = colg - 192; ncols = 64; }
        else if (colg < 320)   { W = w2c; lc = colg - 256; ncols = 64; }
        else if (colg == 320)  { W = w2d; lc = 0;          ncols = 1; }
        ushort8 o;
#pragma unroll
        for (int e = 0; e < 8; ++e)
            o[e] = W ? f2bf(W[(size_t)(kb + e) * ncols + lc]) : (ushort)0;
        *reinterpret_cast<ushort8*>(W2p + (size_t)cc * 8) = o;
    }
}

// ---------------------------------------------------------------------------
// Layer-1 GEMM v10 = v9 with staging register-pressure fix:
//  - staging loops #pragma unroll 2 (caps in-flight loads ~16 VGPR; the
//    fully-unrolled version held up to ~128 and spilled acc era R9/R11/R12)
//  - acc declared after first barrier (shorter lifetime)
// block = 128 rows x 256 cols (ct = hypernet j), 4 waves, wave = 128x64,
// acc[8][4]=128 AGPR; ring[3][4]=48 VGPR B at half-step (K=32) dist-2.
// 1 KB B-frag feeds 8 MFMAs (128 B/MFMA): B L2 demand ~26 B/cyc/CU < ~56.
// Grid bx = mt*4 + ct (S L3-adjacent). 64 KB LDS -> 2 blocks/CU.
// ---------------------------------------------------------------------------
__global__ __launch_bounds__(256, 2) void k_l1(
    const float* __restrict__ S, const ushort* __restrict__ W1p,
    const float* __restrict__ b0, const float* __restrict__ b1,
    const float* __restrict__ b2, const float* __restrict__ b3,
    ushort* __restrict__ hid, int m0)
{
    __shared__ ushort sA[128 * 256];  // 64 KB, 16B-granule swizzle g^(row&7)
    char* sAb = reinterpret_cast<char*>(sA);

    int tid = threadIdx.x, l = tid & 63, w = tid >> 6;  // w in 0..3
    int lr = l & 15, lg = l >> 4;
    int mt = blockIdx.x >> 2, ct = blockIdx.x & 3;
    const float* Srow = S + (size_t)(m0 + mt * 128) * 512;

    bf16x8 ring[3][4];

    // B-frag issue for half-step h (ksg = h, K=32): 4 frags (nf 0..3)
#define ISSUE_B(h, buf)                                                        \
    {                                                                          \
        _Pragma("unroll")                                                      \
        for (int nf = 0; nf < 4; ++nf) {                                       \
            int n16 = ct * 16 + w * 4 + nf;                                    \
            ring[buf][nf] = *reinterpret_cast<const bf16x8*>(                  \
                W1p + ((size_t)(n16 * 16 + (h)) * 64 + l) * 8);                \
        }                                                                      \
    }

    ISSUE_B(0, 0)
    ISSUE_B(1, 1)

    // ---- stage chunk 0: S[128 rows][k 0..256) fp32 -> bf16, swizzled.
    // unroll 2: cap in-flight loads (register pressure, NOT latency, is the
    // binding constraint here — 16 waves/CU of TLP hide staging latency).
#pragma unroll 2
    for (int i = 0; i < 16; ++i) {
        int idx = i * 256 + tid;
        int row = idx >> 5, g = idx & 31;
        const float4* gp = reinterpret_cast<const float4*>(
            Srow + (size_t)row * 512 + g * 8);
        float4 fa = gp[0], fb = gp[1];
        uint4 o;
        o.x = cvtpk(fa.x, fa.y); o.y = cvtpk(fa.z, fa.w);
        o.z = cvtpk(fb.x, fb.y); o.w = cvtpk(fb.z, fb.w);
        *reinterpret_cast<uint4*>(sAb + (size_t)(row * 32 + (g ^ (row & 7))) * 16) = o;
    }
    __syncthreads();

    f32x4 acc[8][4] = {};

#pragma unroll
    for (int h = 0; h < 16; ++h) {  // half-steps: ksg = h, K=32 each
        if (h == 8) {
            __syncthreads();  // all waves done reading chunk 0
#pragma unroll 2
            for (int i = 0; i < 16; ++i) {
                int idx = i * 256 + tid;
                int row = idx >> 5, g = idx & 31;
                const float4* gp = reinterpret_cast<const float4*>(
                    Srow + (size_t)row * 512 + 256 + g * 8);
                float4 fa = gp[0], fb = gp[1];
                uint4 o;
                o.x = cvtpk(fa.x, fa.y); o.y = cvtpk(fa.z, fa.w);
                o.z = cvtpk(fb.x, fb.y); o.w = cvtpk(fb.z, fb.w);
                *reinterpret_cast<uint4*>(
                    sAb + (size_t)(row * 32 + (g ^ (row & 7))) * 16) = o;
            }
            __syncthreads();
        }
        if (h + 2 < 16) ISSUE_B(h + 2, (h + 2) % 3)
        __builtin_amdgcn_sched_barrier(0);  // pin B-issue at region top
        // ---- A fragments: 8 ds_read_b128, reused by the 4 nf
        bf16x8 a[8];
#pragma unroll
        for (int mf = 0; mf < 8; ++mf) {
            int row = mf * 16 + lr;
            int g = (h & 7) * 4 + lg;
            a[mf] = *reinterpret_cast<const bf16x8*>(
                sAb + (size_t)(row * 32 + (g ^ (row & 7))) * 16);
        }
        // ---- 32 MFMA consuming ring[h%3] (issued 2 half-steps ago)
#pragma unroll
        for (int nf = 0; nf < 4; ++nf)
#pragma unroll
            for (int mf = 0; mf < 8; ++mf)
                acc[mf][nf] = __builtin_amdgcn_mfma_f32_16x16x32_bf16(
                    a[mf], ring[h % 3][nf], acc[mf][nf], 0, 0, 0);
    }
#undef ISSUE_B

    __syncthreads();  // sA dead; alias per-wave transpose scratch

    int cb = ct * 256 + w * 64;
    const float* bp = (ct == 0) ? b0 : (ct == 1) ? b1 : (ct == 2) ? b2 : b3;
    ushort* myT = sA + (size_t)w * 2560;  // [128][20] u16 = 5 KB per wave

#pragma unroll
    for (int nf = 0; nf < 4; ++nf) {
        float bv = bp[(cb + nf * 16 + lr) & 255];
#pragma unroll
        for (int mf = 0; mf < 8; ++mf)
#pragma unroll
            for (int r = 0; r < 4; ++r) {
                float v = acc[mf][nf][r] + bv;
                v = v > 0.f ? v : 0.f;
                myT[(mf * 16 + lg * 4 + r) * 20 + lr] = f2bf(v);
            }
#pragma unroll
        for (int i = 0; i < 4; ++i) {
            int idx = i * 64 + l;
            int row = idx >> 1, half = idx & 1;
            ushort8 o = *reinterpret_cast<const ushort8*>(myT + row * 20 + half * 8);
            *reinterpret_cast<ushort8*>(
                hid + (size_t)(mt * 128 + row) * 1024 + cb + nf * 16 + half * 8) = o;
        }
    }
}

// ---------------------------------------------------------------------------
// Layer-2 (4 block GEMMs via MFMA) + mixer, fused. 32 samples / wg. (unchanged)
// ---------------------------------------------------------------------------
__global__ __launch_bounds__(256) void k_l2mix(
    const ushort* __restrict__ hid, const ushort* __restrict__ W2p,
    const float* __restrict__ bw1, const float* __restrict__ bb1,
    const float* __restrict__ bw2, const float* __restrict__ bb2,
    const float* __restrict__ q, float* __restrict__ out, int m0)
{
    __shared__ float sO[32 * 336];
    int tid = threadIdx.x, l = tid & 63, w = tid >> 6;
    int lr = l & 15, lg = l >> 4;
    int sb = blockIdx.x * 32;

    const int fs[5] = {0, 6, 12, 17, 21};
    int jloaded = -1;
    bf16x8 a[2][8];
    for (int f = fs[w]; f < fs[w + 1]; ++f) {
        int j = (f < 12) ? 0 : (f < 16) ? 1 : (f < 20) ? 2 : 3;
        if (j != jloaded) {
#pragma unroll
            for (int mf = 0; mf < 2; ++mf)
#pragma unroll
                for (int ks = 0; ks < 8; ++ks)
                    a[mf][ks] = *reinterpret_cast<const bf16x8*>(
                        hid + (size_t)(sb + mf * 16 + lr) * 1024 + j * 256 + ks * 32 + lg * 8);
            jloaded = j;
        }
        f32x4 acc[2] = {};
#pragma unroll
        for (int ks = 0; ks < 8; ++ks) {
            bf16x8 b = *reinterpret_cast<const bf16x8*>(W2p + ((size_t)(f * 8 + ks) * 64 + l) * 8);
            acc[0] = __builtin_amdgcn_mfma_f32_16x16x32_bf16(a[0][ks], b, acc[0], 0, 0, 0);
            acc[1] = __builtin_amdgcn_mfma_f32_16x16x32_bf16(a[1][ks], b, acc[1], 0, 0, 0);
        }
        int colg = f * 16 + lr;
        float bv = 0.f; bool doabs = false;
        if (colg < 192)       { bv = bw1[colg];       doabs = true; }
        else if (colg < 256)  { bv = bb1[colg - 192]; doabs = false; }
        else if (colg < 320)  { bv = bw2[colg - 256]; doabs = true; }
        else if (colg == 320) { bv = bb2[0];          doabs = false; }
#pragma unroll
        for (int mf = 0; mf < 2; ++mf)
#pragma unroll
            for (int r = 0; r < 4; ++r) {
                float v = acc[mf][r] + bv;
                if (doabs) v = fabsf(v);
                sO[(mf * 16 + lg * 4 + r) * 336 + colg] = v;
            }
    }
    __syncthreads();

    int sm = tid >> 3, oct = tid & 7;
    const float* qs = q + (size_t)(m0 + sb + sm) * 3;
    float q0 = qs[0], q1 = qs[1], q2 = qs[2];
    const float* ob = sO + sm * 336;
    float res[3];
#pragma unroll
    for (int n = 0; n < 3; ++n) {
        float qa, qb, qc;
        if (n == 0)      { qa = q0; qb = q1; qc = q2; }
        else if (n == 1) { qa = q1; qb = q0; qc = q2; }
        else             { qa = q2; qb = q0; qc = q1; }
        float accm = 0.f;
#pragma unroll
        for (int hh = 0; hh < 8; ++hh) {
            int hc = oct * 8 + hh;
            float hv = ob[192 + hc] + qa * ob[hc] + qb * ob[64 + hc] + qc * ob[128 + hc];
            float ev = hv > 0.f ? hv : expm1f(hv);
            accm += ev * ob[256 + hc];
        }
        accm += __shfl_xor(accm, 1);
        accm += __shfl_xor(accm, 2);
        accm += __shfl_xor(accm, 4);
        res[n] = accm;
    }
    if (oct == 0) {
        float b2v = ob[320];
        float* op = out + (size_t)(m0 + sb + sm) * 3;
        op[0] = res[0] + b2v;
        op[1] = res[1] + b2v;
        op[2] = res[2] + b2v;
    }
}

extern "C" void kernel_launch(void* const* d_in, const int* in_sizes, int n_in,
                              void* d_out, int out_size, void* d_ws, size_t ws_size,
                              hipStream_t stream)
{
    const float* q      = (const float*)d_in[0];
    const float* S      = (const float*)d_in[1];
    const float* hw1_W1 = (const float*)d_in[2];
    const float* hw1_b1 = (const float*)d_in[3];
    const float* hw1_W2 = (const float*)d_in[4];
    const float* hw1_b2 = (const float*)d_in[5];
    const float* hb1_W1 = (const float*)d_in[6];
    const float* hb1_b1 = (const float*)d_in[7];
    const float* hb1_W2 = (const float*)d_in[8];
    const float* hb1_b2 = (const float*)d_in[9];
    const float* hw2_W1 = (const float*)d_in[10];
    const float* hw2_b1 = (const float*)d_in[11];
    const float* hw2_W2 = (const float*)d_in[12];
    const float* hw2_b2 = (const float*)d_in[13];
    const float* hb2_W1 = (const float*)d_in[14];
    const float* hb2_b1 = (const float*)d_in[15];
    const float* hb2_W2 = (const float*)d_in[16];
    const float* hb2_b2 = (const float*)d_in[17];

    int TB = in_sizes[1] / 512;

    ushort* W1p = (ushort*)d_ws;
    ushort* W2p = W1p + (size_t)65536 * 8;
    ushort* hid = W2p + (size_t)10752 * 8;
    size_t used = (size_t)(65536 + 10752) * 16;
    size_t hid_cap = (ws_size > used) ? (ws_size - used) : 0;
    long long max_chunk = (long long)(hid_cap / 2048);
    max_chunk &= ~127LL;
    if (max_chunk > TB) max_chunk = TB;
    if (max_chunk < 128) max_chunk = 128;

    k_pack<<<dim3(298), dim3(256), 0, stream>>>(
        hw1_W1, hb1_W1, hw2_W1, hb2_W1,
        hw1_W2, hb1_W2, hw2_W2, hb2_W2, W1p, W2p);

    for (int m0 = 0; m0 < TB; m0 += (int)max_chunk) {
        int mc = TB - m0;
        if (mc > max_chunk) mc = (int)max_chunk;
        k_l1<<<dim3((mc / 128) * 4), dim3(256), 0, stream>>>(
            S, W1p, hw1_b1, hb1_b1, hw2_b1, hb2_b1, hid, m0);
        k_l2mix<<<dim3(mc / 32), dim3(256), 0, stream>>>(
            hid, W2p, hw1_b2, hb1_b2, hw2_b2, hb2_b2, q, (float*)d_out, m0);
    }
}

// Round 14
// 212.115 us; speedup vs baseline: 1.8633x; 1.2685x over previous
//
#include <hip/hip_runtime.h>
#include <hip/hip_bf16.h>

typedef __attribute__((ext_vector_type(8))) __bf16 bf16x8;
typedef __attribute__((ext_vector_type(4))) float f32x4;
typedef __attribute__((ext_vector_type(8))) unsigned short ushort8;
typedef unsigned short ushort;

__device__ __forceinline__ ushort f2bf(float f) {
    unsigned u = __builtin_bit_cast(unsigned, f);
    unsigned r = (u + 0x7fffu + ((u >> 16) & 1u)) >> 16;
    return (ushort)r;
}

__device__ __forceinline__ unsigned cvtpk(float a, float b) {
    unsigned r;
    asm("v_cvt_pk_bf16_f32 %0, %1, %2" : "=v"(r) : "v"(a), "v"(b));
    return r;
}

// async global->LDS, 16B per lane; LDS dest = uniform base + lane*16
__device__ __forceinline__ void gl_lds(const ushort* g, ushort* lds) {
    __builtin_amdgcn_global_load_lds(
        (const __attribute__((address_space(1))) unsigned int*)(const void*)g,
        (__attribute__((address_space(3))) unsigned int*)(void*)lds,
        16, 0, 0);
}

// ---------------------------------------------------------------------------
// k_conv: S fp32 -> Sb bf16 (flat), grid-stride, 16B stores.
// ---------------------------------------------------------------------------
__global__ __launch_bounds__(256) void k_conv(
    const float* __restrict__ S, ushort* __restrict__ Sb, int n8)
{
    int idx = blockIdx.x * 256 + threadIdx.x;
    int stride = gridDim.x * 256;
    for (; idx < n8; idx += stride) {
        const float4* g = reinterpret_cast<const float4*>(S + (size_t)idx * 8);
        float4 fa = g[0], fb = g[1];
        uint4 o;
        o.x = cvtpk(fa.x, fa.y); o.y = cvtpk(fa.z, fa.w);
        o.z = cvtpk(fb.x, fb.y); o.w = cvtpk(fb.z, fb.w);
        *reinterpret_cast<uint4*>(Sb + (size_t)idx * 8) = o;
    }
}

// ---------------------------------------------------------------------------
// k_pack: layer-1 weights into W1q, ordered so each (hypernet j, K-step st)
// B-slice is one contiguous 32 KB block of 1 KB lane-chunks:
//   chunk = ((j*8 + st)*16 + cf)*2 + kl ; lane l, elem e holds
//   B[k = (st*2+kl)*32 + (l>>4)*8 + e][col = cf*16 + (l&15)] of hypernet j.
// W2p unchanged from prior rounds.
// ---------------------------------------------------------------------------
__global__ __launch_bounds__(256) void k_pack(
    const float* __restrict__ w1a, const float* __restrict__ w1b,
    const float* __restrict__ w1c, const float* __restrict__ w1d,
    const float* __restrict__ w2a, const float* __restrict__ w2b,
    const float* __restrict__ w2c, const float* __restrict__ w2d,
    ushort* __restrict__ W1q, ushort* __restrict__ W2p)
{
    int c = blockIdx.x * 256 + threadIdx.x;
    if (c < 65536) {
        int l = c & 63, chunk = c >> 6;
        int kl = chunk & 1, cf = (chunk >> 1) & 15, st = (chunk >> 5) & 7, j = chunk >> 8;
        int ksg = st * 2 + kl;
        int col = cf * 16 + (l & 15);
        int kb = ksg * 32 + (l >> 4) * 8;
        const float* W = (j == 0) ? w1a : (j == 1) ? w1b : (j == 2) ? w1c : w1d;
        ushort8 o;
#pragma unroll
        for (int e = 0; e < 8; ++e) o[e] = f2bf(W[(size_t)(kb + e) * 256 + col]);
        *reinterpret_cast<ushort8*>(W1q + (size_t)c * 8) = o;
    } else if (c < 65536 + 10752) {
        int cc = c - 65536;
        int l = cc & 63, ks = (cc >> 6) & 7, f = cc >> 9;
        int colg = f * 16 + (l & 15);
        int kb = ks * 32 + (l >> 4) * 8;
        const float* W = nullptr; int lc = 0, ncols = 1;
        if (colg < 192)        { W = w2a; lc = colg;       ncols = 192; }
        else if (colg < 256)   { W = w2b; lc = colg - 192; ncols = 64; }
        else if (colg < 320)   { W = w2c; lc = colg - 256; ncols = 64; }
        else if (colg == 320)  { W = w2d; lc = 0;          ncols = 1; }
        ushort8 o;
#pragma unroll
        for (int e = 0; e < 8; ++e)
            o[e] = W ? f2bf(W[(size_t)(kb + e) * ncols + lc]) : (ushort)0;
        *reinterpret_cast<ushort8*>(W2p + (size_t)cc * 8) = o;
    }
}

// ---------------------------------------------------------------------------
// Layer-1 GEMM v11: gload_lds double-buffered 2-barrier counted-vmcnt schedule.
// Block = 256 rows x 256 cols (ct = hypernet j), 512 thr = 8 waves (2M x 4N),
// wave tile 128x64: acc[8][4] = 128 regs; loads are all global_load_lds
// (zero staging VGPRs -> no spill; R9-R13's recurring failure mode).
// LDS: lA 2x32KB (A tile [256 rows][8 k-granules], XOR-swizzled via
// pre-swizzled GLOBAL source + linear dest, rule #21) + lB 2x32KB (contiguous
// W1q slice). Per step: vmcnt(8) counted (T4), barrier, ds_read frags,
// setprio(1) 64 MFMA setprio(0), barrier, STAGE(st+2) into just-freed buffer.
// ---------------------------------------------------------------------------
__global__ __launch_bounds__(512, 2) void k_l1(
    const ushort* __restrict__ Sb, const ushort* __restrict__ W1q,
    const float* __restrict__ b0, const float* __restrict__ b1,
    const float* __restrict__ b2, const float* __restrict__ b3,
    ushort* __restrict__ hid, int m0)
{
    __shared__ ushort lA[2][16384];  // 2 x 32 KB
    __shared__ ushort lB[2][16384];  // 2 x 32 KB

    int tid = threadIdx.x, l = tid & 63, w = tid >> 6;  // w in 0..7
    int lr = l & 15, lg = l >> 4;
    int wm = w >> 2, wn = w & 3;  // 2 M-groups x 4 N-groups
    int mt = blockIdx.x >> 2, ct = blockIdx.x & 3;

    // staging source pointers (per inst i = 0..3); dest is linear granule gi
    const ushort* aSrc[4];
    const ushort* bSrc[4];
#pragma unroll
    for (int i = 0; i < 4; ++i) {
        int gi = (w * 4 + i) * 64 + l;            // granule index 0..2047
        int row = gi >> 3, slot = gi & 7;
        int ksrc = slot ^ (row & 7);              // inverse swizzle on SOURCE
        aSrc[i] = Sb + (size_t)(m0 + mt * 256 + row) * 512 + ksrc * 8;
        bSrc[i] = W1q + (size_t)(ct * 8) * 16384 + (size_t)gi * 8;
    }

#define STAGE(buf, st)                                                         \
    {                                                                          \
        _Pragma("unroll")                                                      \
        for (int i = 0; i < 4; ++i)                                            \
            gl_lds(aSrc[i] + (st) * 64, &lA[buf][(w * 4 + i) * 512]);          \
        _Pragma("unroll")                                                      \
        for (int i = 0; i < 4; ++i)                                            \
            gl_lds(bSrc[i] + (st) * 16384, &lB[buf][(w * 4 + i) * 512]);       \
    }

    STAGE(0, 0)
    STAGE(1, 1)

    f32x4 acc[8][4] = {};

#pragma unroll
    for (int st = 0; st < 8; ++st) {
        const int cur = st & 1;
        // my buf[cur] loads done; allow the 8 newer (st+1) to stay in flight
        if (st < 7) { asm volatile("s_waitcnt vmcnt(8)" ::: "memory"); }
        else        { asm volatile("s_waitcnt vmcnt(0)" ::: "memory"); }
        __builtin_amdgcn_s_barrier();   // all waves' cur-loads landed
        __builtin_amdgcn_sched_barrier(0);

        // B fragments: contiguous 1 KB chunk reads
        bf16x8 bf[2][4];
#pragma unroll
        for (int ks = 0; ks < 2; ++ks)
#pragma unroll
            for (int nf = 0; nf < 4; ++nf)
                bf[ks][nf] = *reinterpret_cast<const bf16x8*>(
                    &lB[cur][(((wn * 4 + nf) * 2 + ks) * 64 + l) * 8]);
#pragma unroll
        for (int ks = 0; ks < 2; ++ks) {
            bf16x8 a[8];
#pragma unroll
            for (int mf = 0; mf < 8; ++mf) {
                int row = wm * 128 + mf * 16 + lr;
                int g = ks * 4 + lg;
                a[mf] = *reinterpret_cast<const bf16x8*>(
                    &lA[cur][(row * 8 + (g ^ (row & 7))) * 8]);
            }
            __builtin_amdgcn_s_setprio(1);
#pragma unroll
            for (int nf = 0; nf < 4; ++nf)
#pragma unroll
                for (int mf = 0; mf < 8; ++mf)
                    acc[mf][nf] = __builtin_amdgcn_mfma_f32_16x16x32_bf16(
                        a[mf], bf[ks][nf], acc[mf][nf], 0, 0, 0);
            __builtin_amdgcn_s_setprio(0);
        }
        __builtin_amdgcn_s_barrier();   // all waves done reading buf[cur]
        __builtin_amdgcn_sched_barrier(0);
        if (st + 2 < 8) STAGE(cur, st + 2)  // overwrite freed buffer
    }
#undef STAGE

    // ---- epilogue: bias + relu -> bf16, via per-wave LDS transpose slice
    __builtin_amdgcn_s_barrier();
    const float* bp = (ct == 0) ? b0 : (ct == 1) ? b1 : (ct == 2) ? b2 : b3;
    ushort* myT = &lA[0][0] + (size_t)w * 2560;  // [128][20] u16 per wave

    int cb = ct * 256 + wn * 64;
#pragma unroll
    for (int nf = 0; nf < 4; ++nf) {
        float bv = bp[(cb + nf * 16 + lr) & 255];
#pragma unroll
        for (int mf = 0; mf < 8; ++mf)
#pragma unroll
            for (int r = 0; r < 4; ++r) {
                float v = acc[mf][nf][r] + bv;
                v = v > 0.f ? v : 0.f;
                myT[(mf * 16 + lg * 4 + r) * 20 + lr] = f2bf(v);
            }
#pragma unroll
        for (int i = 0; i < 4; ++i) {
            int idx = i * 64 + l;
            int row = idx >> 1, half = idx & 1;
            ushort8 o = *reinterpret_cast<const ushort8*>(myT + row * 20 + half * 8);
            *reinterpret_cast<ushort8*>(
                hid + (size_t)(m0 + mt * 256 + wm * 128 + row) * 1024 +
                cb + nf * 16 + half * 8) = o;
        }
    }
}

// ---------------------------------------------------------------------------
// Layer-2 (4 block GEMMs via MFMA) + mixer, fused. 32 samples / wg. (unchanged)
// ---------------------------------------------------------------------------
__global__ __launch_bounds__(256) void k_l2mix(
    const ushort* __restrict__ hid, const ushort* __restrict__ W2p,
    const float* __restrict__ bw1, const float* __restrict__ bb1,
    const float* __restrict__ bw2, const float* __restrict__ bb2,
    const float* __restrict__ q, float* __restrict__ out, int m0)
{
    __shared__ float sO[32 * 336];
    int tid = threadIdx.x, l = tid & 63, w = tid >> 6;
    int lr = l & 15, lg = l >> 4;
    int sb = blockIdx.x * 32;

    const int fs[5] = {0, 6, 12, 17, 21};
    int jloaded = -1;
    bf16x8 a[2][8];
    for (int f = fs[w]; f < fs[w + 1]; ++f) {
        int j = (f < 12) ? 0 : (f < 16) ? 1 : (f < 20) ? 2 : 3;
        if (j != jloaded) {
#pragma unroll
            for (int mf = 0; mf < 2; ++mf)
#pragma unroll
                for (int ks = 0; ks < 8; ++ks)
                    a[mf][ks] = *reinterpret_cast<const bf16x8*>(
                        hid + (size_t)(sb + mf * 16 + lr) * 1024 + j * 256 + ks * 32 + lg * 8);
            jloaded = j;
        }
        f32x4 acc[2] = {};
#pragma unroll
        for (int ks = 0; ks < 8; ++ks) {
            bf16x8 b = *reinterpret_cast<const bf16x8*>(W2p + ((size_t)(f * 8 + ks) * 64 + l) * 8);
            acc[0] = __builtin_amdgcn_mfma_f32_16x16x32_bf16(a[0][ks], b, acc[0], 0, 0, 0);
            acc[1] = __builtin_amdgcn_mfma_f32_16x16x32_bf16(a[1][ks], b, acc[1], 0, 0, 0);
        }
        int colg = f * 16 + lr;
        float bv = 0.f; bool doabs = false;
        if (colg < 192)       { bv = bw1[colg];       doabs = true; }
        else if (colg < 256)  { bv = bb1[colg - 192]; doabs = false; }
        else if (colg < 320)  { bv = bw2[colg - 256]; doabs = true; }
        else if (colg == 320) { bv = bb2[0];          doabs = false; }
#pragma unroll
        for (int mf = 0; mf < 2; ++mf)
#pragma unroll
            for (int r = 0; r < 4; ++r) {
                float v = acc[mf][r] + bv;
                if (doabs) v = fabsf(v);
                sO[(mf * 16 + lg * 4 + r) * 336 + colg] = v;
            }
    }
    __syncthreads();

    int sm = tid >> 3, oct = tid & 7;
    const float* qs = q + (size_t)(m0 + sb + sm) * 3;
    float q0 = qs[0], q1 = qs[1], q2 = qs[2];
    const float* ob = sO + sm * 336;
    float res[3];
#pragma unroll
    for (int n = 0; n < 3; ++n) {
        float qa, qb, qc;
        if (n == 0)      { qa = q0; qb = q1; qc = q2; }
        else if (n == 1) { qa = q1; qb = q0; qc = q2; }
        else             { qa = q2; qb = q0; qc = q1; }
        float accm = 0.f;
#pragma unroll
        for (int hh = 0; hh < 8; ++hh) {
            int hc = oct * 8 + hh;
            float hv = ob[192 + hc] + qa * ob[hc] + qb * ob[64 + hc] + qc * ob[128 + hc];
            float ev = hv > 0.f ? hv : expm1f(hv);
            accm += ev * ob[256 + hc];
        }
        accm += __shfl_xor(accm, 1);
        accm += __shfl_xor(accm, 2);
        accm += __shfl_xor(accm, 4);
        res[n] = accm;
    }
    if (oct == 0) {
        float b2v = ob[320];
        float* op = out + (size_t)(m0 + sb + sm) * 3;
        op[0] = res[0] + b2v;
        op[1] = res[1] + b2v;
        op[2] = res[2] + b2v;
    }
}

extern "C" void kernel_launch(void* const* d_in, const int* in_sizes, int n_in,
                              void* d_out, int out_size, void* d_ws, size_t ws_size,
                              hipStream_t stream)
{
    const float* q      = (const float*)d_in[0];
    const float* S      = (const float*)d_in[1];
    const float* hw1_W1 = (const float*)d_in[2];
    const float* hw1_b1 = (const float*)d_in[3];
    const float* hw1_W2 = (const float*)d_in[4];
    const float* hw1_b2 = (const float*)d_in[5];
    const float* hb1_W1 = (const float*)d_in[6];
    const float* hb1_b1 = (const float*)d_in[7];
    const float* hb1_W2 = (const float*)d_in[8];
    const float* hb1_b2 = (const float*)d_in[9];
    const float* hw2_W1 = (const float*)d_in[10];
    const float* hw2_b1 = (const float*)d_in[11];
    const float* hw2_W2 = (const float*)d_in[12];
    const float* hw2_b2 = (const float*)d_in[13];
    const float* hb2_W1 = (const float*)d_in[14];
    const float* hb2_b1 = (const float*)d_in[15];
    const float* hb2_W2 = (const float*)d_in[16];
    const float* hb2_b2 = (const float*)d_in[17];

    int TB = in_sizes[1] / 512;

    ushort* W1q = (ushort*)d_ws;                       // 1 MB
    ushort* W2p = W1q + (size_t)65536 * 8;             // 168 KB
    ushort* Sbb = W2p + (size_t)10752 * 8;             // TB*512 bf16 = 67 MB
    ushort* hid = Sbb + (size_t)TB * 512;
    size_t used = (size_t)(65536 + 10752) * 16 + (size_t)TB * 1024;
    size_t hid_cap = (ws_size > used) ? (ws_size - used) : 0;
    long long max_chunk = (long long)(hid_cap / 2048);  // samples
    max_chunk &= ~255LL;
    if (max_chunk > TB) max_chunk = TB;
    if (max_chunk < 256) max_chunk = 256;  // best effort

    k_pack<<<dim3(298), dim3(256), 0, stream>>>(
        hw1_W1, hb1_W1, hw2_W1, hb2_W1,
        hw1_W2, hb1_W2, hw2_W2, hb2_W2, W1q, W2p);
    k_conv<<<dim3(2048), dim3(256), 0, stream>>>(S, Sbb, TB * 64);

    for (int m0 = 0; m0 < TB; m0 += (int)max_chunk) {
        int mc = TB - m0;
        if (mc > max_chunk) mc = (int)max_chunk;
        k_l1<<<dim3((mc / 256) * 4), dim3(512), 0, stream>>>(
            Sbb, W1q, hw1_b1, hb1_b1, hw2_b1, hb2_b1, hid, m0);
        k_l2mix<<<dim3(mc / 32), dim3(256), 0, stream>>>(
            hid, W2p, hw1_b2, hb1_b2, hw2_b2, hb2_b2, q, (float*)d_out, m0);
    }
}

// Round 15
// 207.618 us; speedup vs baseline: 1.9037x; 1.0217x over previous
//
#include <hip/hip_runtime.h>
#include <hip/hip_bf16.h>

typedef __attribute__((ext_vector_type(8))) __bf16 bf16x8;
typedef __attribute__((ext_vector_type(4))) float f32x4;
typedef __attribute__((ext_vector_type(8))) unsigned short ushort8;
typedef unsigned short ushort;

__device__ __forceinline__ ushort f2bf(float f) {
    unsigned u = __builtin_bit_cast(unsigned, f);
    unsigned r = (u + 0x7fffu + ((u >> 16) & 1u)) >> 16;
    return (ushort)r;
}

__device__ __forceinline__ unsigned cvtpk(float a, float b) {
    unsigned r;
    asm("v_cvt_pk_bf16_f32 %0, %1, %2" : "=v"(r) : "v"(a), "v"(b));
    return r;
}

// async global->LDS, 16B per lane; LDS dest = wave-uniform base + lane*16
__device__ __forceinline__ void gl_lds(const ushort* g, ushort* lds) {
    __builtin_amdgcn_global_load_lds(
        (const __attribute__((address_space(1))) unsigned int*)(const void*)g,
        (__attribute__((address_space(3))) unsigned int*)(void*)lds,
        16, 0, 0);
}

// ---------------------------------------------------------------------------
// k_conv: S fp32 -> Sb bf16 (flat), grid-stride, 16B stores. Also warms L3.
// ---------------------------------------------------------------------------
__global__ __launch_bounds__(256) void k_conv(
    const float* __restrict__ S, ushort* __restrict__ Sb, int n8)
{
    int idx = blockIdx.x * 256 + threadIdx.x;
    int stride = gridDim.x * 256;
    for (; idx < n8; idx += stride) {
        const float4* g = reinterpret_cast<const float4*>(S + (size_t)idx * 8);
        float4 fa = g[0], fb = g[1];
        uint4 o;
        o.x = cvtpk(fa.x, fa.y); o.y = cvtpk(fa.z, fa.w);
        o.z = cvtpk(fb.x, fb.y); o.w = cvtpk(fb.z, fb.w);
        *reinterpret_cast<uint4*>(Sb + (size_t)idx * 8) = o;
    }
}

// ---------------------------------------------------------------------------
// k_pack: W1q ordered so each (hypernet j, K-granule ksg of 32) B-slice is a
// contiguous 16 KB block of 16 lane-chunks:
//   chunk = (j*16 + ksg)*16 + cf ; lane l, elem e holds
//   B[k = ksg*32 + (l>>4)*8 + e][col = cf*16 + (l&15)] of hypernet j.
// W2p unchanged.
// ---------------------------------------------------------------------------
__global__ __launch_bounds__(256) void k_pack(
    const float* __restrict__ w1a, const float* __restrict__ w1b,
    const float* __restrict__ w1c, const float* __restrict__ w1d,
    const float* __restrict__ w2a, const float* __restrict__ w2b,
    const float* __restrict__ w2c, const float* __restrict__ w2d,
    ushort* __restrict__ W1q, ushort* __restrict__ W2p)
{
    int c = blockIdx.x * 256 + threadIdx.x;
    if (c < 65536) {
        int l = c & 63, chunk = c >> 6;
        int cf = chunk & 15, ksg = (chunk >> 4) & 15, j = chunk >> 8;
        int col = cf * 16 + (l & 15);
        int kb = ksg * 32 + (l >> 4) * 8;
        const float* W = (j == 0) ? w1a : (j == 1) ? w1b : (j == 2) ? w1c : w1d;
        ushort8 o;
#pragma unroll
        for (int e = 0; e < 8; ++e) o[e] = f2bf(W[(size_t)(kb + e) * 256 + col]);
        *reinterpret_cast<ushort8*>(W1q + (size_t)c * 8) = o;
    } else if (c < 65536 + 10752) {
        int cc = c - 65536;
        int l = cc & 63, ks = (cc >> 6) & 7, f = cc >> 9;
        int colg = f * 16 + (l & 15);
        int kb = ks * 32 + (l >> 4) * 8;
        const float* W = nullptr; int lc = 0, ncols = 1;
        if (colg < 192)        { W = w2a; lc = colg;       ncols = 192; }
        else if (colg < 256)   { W = w2b; lc = colg - 192; ncols = 64; }
        else if (colg < 320)   { W = w2c; lc = colg - 256; ncols = 64; }
        else if (colg == 320)  { W = w2d; lc = 0;          ncols = 1; }
        ushort8 o;
#pragma unroll
        for (int e = 0; e < 8; ++e)
            o[e] = W ? f2bf(W[(size_t)(kb + e) * ncols + lc]) : (ushort)0;
        *reinterpret_cast<ushort8*>(W2p + (size_t)cc * 8) = o;
    }
}

// ---------------------------------------------------------------------------
// Layer-1 GEMM v12: gload_lds double-buffer, counted vmcnt, sized for
// 2 blocks/CU (the R14 single-block lockstep fix, per m114 implicit overlap).
// Block = 128 rows x 256 cols (ct = hypernet j), 256 thr = 4 waves; wave w
// owns cols w*64, all 128 rows: acc[8][4] = 128 regs. BK=32, 16 steps.
// LDS 48 KB (lA 2x8KB + lB 2x16KB) -> 2 blocks/CU at launch_bounds(256,2)
// (2 waves/SIMD, 256 unified regs each). 6 gl_lds/wave/step, vmcnt(6).
// A swizzle via pre-swizzled global source slot^(row&3) (rule #21).
// Frag LDS addresses are step-invariant (hoisted by compiler).
// ---------------------------------------------------------------------------
__global__ __launch_bounds__(256, 2) void k_l1(
    const ushort* __restrict__ Sb, const ushort* __restrict__ W1q,
    const float* __restrict__ b0, const float* __restrict__ b1,
    const float* __restrict__ b2, const float* __restrict__ b3,
    ushort* __restrict__ hid, int m0)
{
    __shared__ ushort smem[24576];  // 48 KB: lA = [0,8192), lB = [8192,24576)

    int tid = threadIdx.x, l = tid & 63, w = tid >> 6;  // w in 0..3
    int lr = l & 15, lg = l >> 4;
    int mt = blockIdx.x >> 2, ct = blockIdx.x & 3;

    // --- staging source pointers (step-invariant bases)
    const ushort* aS[2];  ushort* aD[2];
    const ushort* bS[4];  ushort* bD[4];
#pragma unroll
    for (int i = 0; i < 2; ++i) {
        int ch = w * 2 + i;                        // A chunk 0..7
        int row = ch * 16 + (l >> 2);
        int ss = (l & 3) ^ ((l >> 2) & 3);         // inverse swizzle on SOURCE
        aS[i] = Sb + (size_t)(m0 + mt * 128 + row) * 512 + ss * 8;
        aD[i] = smem + ch * 512;                   // + buf*4096
    }
#pragma unroll
    for (int i = 0; i < 4; ++i) {
        int cf = w * 4 + i;                        // B chunk 0..15
        bS[i] = W1q + (size_t)(ct * 16) * 8192 + cf * 512 + (size_t)l * 8;
        bD[i] = smem + 8192 + cf * 512;            // + buf*8192
    }

#define STAGE(buf, st)                                                         \
    {                                                                          \
        _Pragma("unroll")                                                      \
        for (int i = 0; i < 2; ++i)                                            \
            gl_lds(aS[i] + (st) * 32, aD[i] + (buf) * 4096);                   \
        _Pragma("unroll")                                                      \
        for (int i = 0; i < 4; ++i)                                            \
            gl_lds(bS[i] + (size_t)(st) * 8192, bD[i] + (buf) * 8192);         \
    }

    STAGE(0, 0)
    STAGE(1, 1)

    f32x4 acc[8][4] = {};

#pragma unroll
    for (int st = 0; st < 16; ++st) {
        const int cur = st & 1;
        if (st < 15) { asm volatile("s_waitcnt vmcnt(6)" ::: "memory"); }
        else         { asm volatile("s_waitcnt vmcnt(0)" ::: "memory"); }
        __builtin_amdgcn_s_barrier();   // all waves' cur-tile loads landed
        __builtin_amdgcn_sched_barrier(0);

        const ushort* A  = smem + cur * 4096;
        const ushort* Bt = smem + 8192 + cur * 8192;
        bf16x8 bf[4];
#pragma unroll
        for (int nf = 0; nf < 4; ++nf)
            bf[nf] = *reinterpret_cast<const bf16x8*>(
                &Bt[(size_t)((w * 4 + nf) * 64 + l) * 8]);
        bf16x8 a[8];
#pragma unroll
        for (int mf = 0; mf < 8; ++mf) {
            int row = mf * 16 + lr;
            int g = row * 4 + (lg ^ (row & 3));
            a[mf] = *reinterpret_cast<const bf16x8*>(&A[(size_t)g * 8]);
        }
        __builtin_amdgcn_s_setprio(1);
#pragma unroll
        for (int nf = 0; nf < 4; ++nf)
#pragma unroll
            for (int mf = 0; mf < 8; ++mf)
                acc[mf][nf] = __builtin_amdgcn_mfma_f32_16x16x32_bf16(
                    a[mf], bf[nf], acc[mf][nf], 0, 0, 0);
        __builtin_amdgcn_s_setprio(0);
        __builtin_amdgcn_s_barrier();   // all waves done reading buf[cur]
        __builtin_amdgcn_sched_barrier(0);
        if (st + 2 < 16) STAGE(cur, st + 2)
    }
#undef STAGE

    // ---- epilogue: bias + relu -> bf16 via per-wave LDS transpose slice
    __builtin_amdgcn_s_barrier();
    const float* bp = (ct == 0) ? b0 : (ct == 1) ? b1 : (ct == 2) ? b2 : b3;
    ushort* myT = smem + (size_t)w * 2560;  // [128][20] u16 per wave

    int cb = ct * 256 + w * 64;
#pragma unroll
    for (int nf = 0; nf < 4; ++nf) {
        float bv = bp[(cb + nf * 16 + lr) & 255];
#pragma unroll
        for (int mf = 0; mf < 8; ++mf)
#pragma unroll
            for (int r = 0; r < 4; ++r) {
                float v = acc[mf][nf][r] + bv;
                v = v > 0.f ? v : 0.f;
                myT[(mf * 16 + lg * 4 + r) * 20 + lr] = f2bf(v);
            }
#pragma unroll
        for (int i = 0; i < 4; ++i) {
            int idx = i * 64 + l;
            int row = idx >> 1, half = idx & 1;
            ushort8 o = *reinterpret_cast<const ushort8*>(myT + row * 20 + half * 8);
            *reinterpret_cast<ushort8*>(
                hid + (size_t)(m0 + mt * 128 + row) * 1024 +
                cb + nf * 16 + half * 8) = o;
        }
    }
}

// ---------------------------------------------------------------------------
// Layer-2 (4 block GEMMs via MFMA) + mixer, fused. 32 samples / wg. (unchanged)
// ---------------------------------------------------------------------------
__global__ __launch_bounds__(256) void k_l2mix(
    const ushort* __restrict__ hid, const ushort* __restrict__ W2p,
    const float* __restrict__ bw1, const float* __restrict__ bb1,
    const float* __restrict__ bw2, const float* __restrict__ bb2,
    const float* __restrict__ q, float* __restrict__ out, int m0)
{
    __shared__ float sO[32 * 336];
    int tid = threadIdx.x, l = tid & 63, w = tid >> 6;
    int lr = l & 15, lg = l >> 4;
    int sb = blockIdx.x * 32;

    const int fs[5] = {0, 6, 12, 17, 21};
    int jloaded = -1;
    bf16x8 a[2][8];
    for (int f = fs[w]; f < fs[w + 1]; ++f) {
        int j = (f < 12) ? 0 : (f < 16) ? 1 : (f < 20) ? 2 : 3;
        if (j != jloaded) {
#pragma unroll
            for (int mf = 0; mf < 2; ++mf)
#pragma unroll
                for (int ks = 0; ks < 8; ++ks)
                    a[mf][ks] = *reinterpret_cast<const bf16x8*>(
                        hid + (size_t)(m0 + sb + mf * 16 + lr) * 1024 + j * 256 + ks * 32 + lg * 8);
            jloaded = j;
        }
        f32x4 acc[2] = {};
#pragma unroll
        for (int ks = 0; ks < 8; ++ks) {
            bf16x8 b = *reinterpret_cast<const bf16x8*>(W2p + ((size_t)(f * 8 + ks) * 64 + l) * 8);
            acc[0] = __builtin_amdgcn_mfma_f32_16x16x32_bf16(a[0][ks], b, acc[0], 0, 0, 0);
            acc[1] = __builtin_amdgcn_mfma_f32_16x16x32_bf16(a[1][ks], b, acc[1], 0, 0, 0);
        }
        int colg = f * 16 + lr;
        float bv = 0.f; bool doabs = false;
        if (colg < 192)       { bv = bw1[colg];       doabs = true; }
        else if (colg < 256)  { bv = bb1[colg - 192]; doabs = false; }
        else if (colg < 320)  { bv = bw2[colg - 256]; doabs = true; }
        else if (colg == 320) { bv = bb2[0];          doabs = false; }
#pragma unroll
        for (int mf = 0; mf < 2; ++mf)
#pragma unroll
            for (int r = 0; r < 4; ++r) {
                float v = acc[mf][r] + bv;
                if (doabs) v = fabsf(v);
                sO[(mf * 16 + lg * 4 + r) * 336 + colg] = v;
            }
    }
    __syncthreads();

    int sm = tid >> 3, oct = tid & 7;
    const float* qs = q + (size_t)(m0 + sb + sm) * 3;
    float q0 = qs[0], q1 = qs[1], q2 = qs[2];
    const float* ob = sO + sm * 336;
    float res[3];
#pragma unroll
    for (int n = 0; n < 3; ++n) {
        float qa, qb, qc;
        if (n == 0)      { qa = q0; qb = q1; qc = q2; }
        else if (n == 1) { qa = q1; qb = q0; qc = q2; }
        else             { qa = q2; qb = q0; qc = q1; }
        float accm = 0.f;
#pragma unroll
        for (int hh = 0; hh < 8; ++hh) {
            int hc = oct * 8 + hh;
            float hv = ob[192 + hc] + qa * ob[hc] + qb * ob[64 + hc] + qc * ob[128 + hc];
            float ev = hv > 0.f ? hv : expm1f(hv);
            accm += ev * ob[256 + hc];
        }
        accm += __shfl_xor(accm, 1);
        accm += __shfl_xor(accm, 2);
        accm += __shfl_xor(accm, 4);
        res[n] = accm;
    }
    if (oct == 0) {
        float b2v = ob[320];
        float* op = out + (size_t)(m0 + sb + sm) * 3;
        op[0] = res[0] + b2v;
        op[1] = res[1] + b2v;
        op[2] = res[2] + b2v;
    }
}

extern "C" void kernel_launch(void* const* d_in, const int* in_sizes, int n_in,
                              void* d_out, int out_size, void* d_ws, size_t ws_size,
                              hipStream_t stream)
{
    const float* q      = (const float*)d_in[0];
    const float* S      = (const float*)d_in[1];
    const float* hw1_W1 = (const float*)d_in[2];
    const float* hw1_b1 = (const float*)d_in[3];
    const float* hw1_W2 = (const float*)d_in[4];
    const float* hw1_b2 = (const float*)d_in[5];
    const float* hb1_W1 = (const float*)d_in[6];
    const float* hb1_b1 = (const float*)d_in[7];
    const float* hb1_W2 = (const float*)d_in[8];
    const float* hb1_b2 = (const float*)d_in[9];
    const float* hw2_W1 = (const float*)d_in[10];
    const float* hw2_b1 = (const float*)d_in[11];
    const float* hw2_W2 = (const float*)d_in[12];
    const float* hw2_b2 = (const float*)d_in[13];
    const float* hb2_W1 = (const float*)d_in[14];
    const float* hb2_b1 = (const float*)d_in[15];
    const float* hb2_W2 = (const float*)d_in[16];
    const float* hb2_b2 = (const float*)d_in[17];

    int TB = in_sizes[1] / 512;

    ushort* W1q = (ushort*)d_ws;                       // 1 MB
    ushort* W2p = W1q + (size_t)65536 * 8;             // 168 KB
    ushort* Sbb = W2p + (size_t)10752 * 8;             // TB*512 bf16 = 67 MB
    ushort* hid = Sbb + (size_t)TB * 512;
    size_t used = (size_t)(65536 + 10752) * 16 + (size_t)TB * 1024;
    size_t hid_cap = (ws_size > used) ? (ws_size - used) : 0;
    long long max_chunk = (long long)(hid_cap / 2048);  // samples
    max_chunk &= ~127LL;
    if (max_chunk > TB) max_chunk = TB;
    if (max_chunk < 128) max_chunk = 128;  // best effort

    k_pack<<<dim3(298), dim3(256), 0, stream>>>(
        hw1_W1, hb1_W1, hw2_W1, hb2_W1,
        hw1_W2, hb1_W2, hw2_W2, hb2_W2, W1q, W2p);
    k_conv<<<dim3(2048), dim3(256), 0, stream>>>(S, Sbb, TB * 64);

    for (int m0 = 0; m0 < TB; m0 += (int)max_chunk) {
        int mc = TB - m0;
        if (mc > max_chunk) mc = (int)max_chunk;
        k_l1<<<dim3((mc / 128) * 4), dim3(256), 0, stream>>>(
            Sbb, W1q, hw1_b1, hb1_b1, hw2_b1, hb2_b1, hid, m0);
        k_l2mix<<<dim3(mc / 32), dim3(256), 0, stream>>>(
            hid, W2p, hw1_b2, hb1_b2, hw2_b2, hb2_b2, q, (float*)d_out, m0);
    }
}